// Round 10
// baseline (238.493 us; speedup 1.0000x reference)
//
#include <hip/hip_runtime.h>
#include <hip/hip_bf16.h>

// Problem: B=16384, J=12, Q=7, O=5, H1=H2=128.  Output: fp32 [B,Q,O].
// Single-dispatch design: each block deterministically re-derives the judge
// bucketing (no atomics, no workspace, no pre-kernels) and builds MFMA
// B-fragments on the fly from raw weights (index math identical to the
// R8/R9-verified combine_body).
#define B_TOT 16384
#define NQ 7

typedef float v4f __attribute__((ext_vector_type(4)));
typedef _Float16 v8h __attribute__((ext_vector_type(8)));

#define Z_STRIDE 136   // u16 row stride (16B-aligned rows)
#define A_STRIDE 72
#define GRID_MAIN 512

// ---------------- helpers ----------------
__device__ __forceinline__ float ldf(const float* p) { return *p; }
__device__ __forceinline__ float ldf(const __hip_bfloat16* p) { return __bfloat162float(*p); }
__device__ __forceinline__ float sigmoidf_(float v) { return 1.0f / (1.0f + __expf(-v)); }
__device__ __forceinline__ unsigned short f2h(float f) {
    _Float16 h = (_Float16)f; return __builtin_bit_cast(unsigned short, h);
}
__device__ __forceinline__ float h2f(unsigned short u) {
    return (float)__builtin_bit_cast(_Float16, u);
}
__device__ __forceinline__ unsigned pack2(float a, float b) {
    return (unsigned)f2h(a) | ((unsigned)f2h(b) << 16);
}
__device__ __forceinline__ v8h bc8h(uint4 u) { return __builtin_bit_cast(v8h, u); }

// ---------------- on-the-fly B-fragment builders (math == combine_body) ----
template<typename T>
__device__ __forceinline__ uint4 bfrag_w1(const T* W1, const T* W1a,
                                          int j, int ks, int n, int l) {
    int kb = ks*32 + ((l >> 4) << 3);
    unsigned r[4];
    #pragma unroll
    for (int p = 0; p < 4; ++p) {
        int k0 = kb + 2*p, k1 = k0 + 1;
        float v0 = (k0 < 42) ? (ldf(W1 + k0*128 + n) + ldf(W1a + j*5376 + k0*128 + n)) : 0.f;
        float v1 = (k1 < 42) ? (ldf(W1 + k1*128 + n) + ldf(W1a + j*5376 + k1*128 + n)) : 0.f;
        r[p] = pack2(v0, v1);
    }
    uint4 u; u.x = r[0]; u.y = r[1]; u.z = r[2]; u.w = r[3]; return u;
}
template<typename T>
__device__ __forceinline__ uint4 bfrag_w2(const T* W2, const T* W2a,
                                          int j, int ks, int n, int l) {
    int kb = ks*32 + ((l >> 4) << 3);
    unsigned r[4];
    #pragma unroll
    for (int p = 0; p < 4; ++p) {
        int k0 = kb + 2*p, k1 = k0 + 1;
        float v0 = ldf(W2 + k0*128 + n) + ldf(W2a + (j*129 + k0)*128 + n);
        float v1 = ldf(W2 + k1*128 + n) + ldf(W2a + (j*129 + k1)*128 + n);
        r[p] = pack2(v0, v1);
    }
    uint4 u; u.x = r[0]; u.y = r[1]; u.z = r[2]; u.w = r[3]; return u;
}
template<typename T>
__device__ __forceinline__ uint4 bfrag_v3(const T* V, const T* Va,
                                          int j, int q, int ks, int l) {
    uint4 u; u.x = 0; u.y = 0; u.z = 0; u.w = 0;
    int n = l & 15;
    if (n >= 5) return u;                     // zero-padded columns
    int kb = ks*32 + ((l >> 4) << 3);
    unsigned r[4];
    #pragma unroll
    for (int p = 0; p < 4; ++p) {
        int k0 = kb + 2*p, k1 = k0 + 1;
        float v0 = ldf(V + q*645 + k0*5 + n) + ldf(Va + j*4515 + q*645 + k0*5 + n);
        float v1 = ldf(V + q*645 + k1*5 + n) + ldf(Va + j*4515 + q*645 + k1*5 + n);
        r[p] = pack2(v0, v1);
    }
    u.x = r[0]; u.y = r[1]; u.z = r[2]; u.w = r[3]; return u;
}

// ---------------- per-tile compute pipeline (R9-verified MFMA core) ----------
template<typename T>
__device__ __forceinline__ void do_tile(
    const T* __restrict__ x,
    const T* __restrict__ W1, const T* __restrict__ W1a,
    const T* __restrict__ W2, const T* __restrict__ W2a,
    const T* __restrict__ V,  const T* __restrict__ Va,
    float* __restrict__ out,
    unsigned short* z1L, unsigned short* z2A, float* lg, const int* pvals,
    int jT, int valid, int tid, int l, int w, int quad, int m)
{
    // ---- staging: zero A1, z1L bias col ----
    {
        unsigned* a32 = (unsigned*)z2A;
        for (int i = tid; i < 112 * A_STRIDE / 2; i += 256) a32[i] = 0u;
        if (tid < 112) z1L[tid * Z_STRIDE] = 0x3C00;       // 1.0h
    }
    __syncthreads();
    // ---- staging: A1 rows {1, x0..x4} at col q*6 ----
    if (tid < 112) {
        int bl = tid / 7, q = tid - bl*7;
        int bg = pvals[bl];
        const T* xp = x + bg*35 + q*5;
        float x0 = ldf(xp), x1 = ldf(xp+1), x2 = ldf(xp+2), x3 = ldf(xp+3), x4 = ldf(xp+4);
        unsigned* rp = (unsigned*)&z2A[tid * A_STRIDE + q*6];
        rp[0] = 0x3C00u | ((unsigned)f2h(x0) << 16);
        rp[1] = pack2(x1, x2);
        rp[2] = pack2(x3, x4);
    }
    __syncthreads();

    // ---- layer 1: [112 x 64] x [64 x 128] ----
    {
        #pragma unroll
        for (int nt2 = 0; nt2 < 2; ++nt2) {
            const int nt = w*2 + nt2;
            const int n = nt*16 + m;
            const uint4 b0 = bfrag_w1(W1, W1a, jT, 0, n, l);
            const uint4 b1 = bfrag_w1(W1, W1a, jT, 1, n, l);
            #pragma unroll 1
            for (int mt = 0; mt < 7; ++mt) {
                const uint4 a0 = *(const uint4*)&z2A[(mt*16 + m)*A_STRIDE + quad*8];
                const uint4 a1 = *(const uint4*)&z2A[(mt*16 + m)*A_STRIDE + 32 + quad*8];
                v4f acc2 = {0.f, 0.f, 0.f, 0.f};
                acc2 = __builtin_amdgcn_mfma_f32_16x16x32_f16(bc8h(a0), bc8h(b0), acc2, 0, 0, 0);
                acc2 = __builtin_amdgcn_mfma_f32_16x16x32_f16(bc8h(a1), bc8h(b1), acc2, 0, 0, 0);
                const int col = nt*16 + m;
                #pragma unroll
                for (int i = 0; i < 4; ++i) {
                    int row = mt*16 + quad*4 + i;
                    z1L[row*Z_STRIDE + 1 + col] = f2h(sigmoidf_(acc2[i]));
                }
            }
        }
    }
    __syncthreads();

    // ---- layer 2: [112 x 128] x [128 x 128] + i'=128 fixup ----
    {
        if (tid < 112) z2A[tid * Z_STRIDE] = 0x3C00;       // z2 bias col
        #pragma unroll
        for (int nt2 = 0; nt2 < 2; ++nt2) {
            const int nt = w*2 + nt2;
            const int n = nt*16 + m;
            uint4 Bv[4];
            #pragma unroll
            for (int ks = 0; ks < 4; ++ks) Bv[ks] = bfrag_w2(W2, W2a, jT, ks, n, l);
            const float wl = ldf(W2 + 128*128 + n) + ldf(W2a + (jT*129 + 128)*128 + n);
            #pragma unroll 1
            for (int mt = 0; mt < 7; ++mt) {
                v4f acc2 = {0.f, 0.f, 0.f, 0.f};
                #pragma unroll
                for (int ks = 0; ks < 4; ++ks) {
                    const uint4 a = *(const uint4*)&z1L[(mt*16 + m)*Z_STRIDE + ks*32 + quad*8];
                    acc2 = __builtin_amdgcn_mfma_f32_16x16x32_f16(bc8h(a), bc8h(Bv[ks]), acc2, 0, 0, 0);
                }
                const int col = nt*16 + m;
                #pragma unroll
                for (int i = 0; i < 4; ++i) {
                    int row = mt*16 + quad*4 + i;
                    float zl = h2f(z1L[row*Z_STRIDE + 128]);   // z1[h=127]
                    float vv = acc2[i] + zl * wl;
                    z2A[row*Z_STRIDE + 1 + col] = f2h(sigmoidf_(vv));
                }
            }
        }
    }
    __syncthreads();

    // ---- layer 3: per q [16 x 128] x [128 x 16(5)] + fixup -> logits ----
    {
        #pragma unroll 1
        for (int qi = 0; qi < 2; ++qi) {
            const int q = w + qi*4;
            if (q > 6) break;
            v4f acc2 = {0.f, 0.f, 0.f, 0.f};
            #pragma unroll
            for (int ks = 0; ks < 4; ++ks) {
                const uint4 b = bfrag_v3(V, Va, jT, q, ks, l);
                const uint4 a = *(const uint4*)&z2A[(m*7 + q)*Z_STRIDE + ks*32 + quad*8];
                acc2 = __builtin_amdgcn_mfma_f32_16x16x32_f16(bc8h(a), bc8h(b), acc2, 0, 0, 0);
            }
            const float vl = (m < 5)
                ? (ldf(V + q*645 + 640 + m) + ldf(Va + jT*4515 + q*645 + 640 + m)) : 0.f;
            #pragma unroll
            for (int i = 0; i < 4; ++i) {
                int bloc = quad*4 + i;
                float zl = h2f(z2A[(bloc*7 + q)*Z_STRIDE + 128]);  // z2[h'=127]
                float logit = acc2[i] + zl * vl;
                if (m < 5) lg[(bloc*7 + q)*8 + m] = logit;
            }
        }
    }
    __syncthreads();

    // ---- softmax + store ----
    if (tid < 112) {
        int bl = tid / 7, q = tid - bl*7;
        const float* pr = &lg[tid*8];
        float p0 = pr[0], p1 = pr[1], p2 = pr[2], p3 = pr[3], p4 = pr[4];
        float mx = fmaxf(fmaxf(fmaxf(p0, p1), fmaxf(p2, p3)), p4);
        float e0 = __expf(p0 - mx), e1 = __expf(p1 - mx), e2 = __expf(p2 - mx),
              e3 = __expf(p3 - mx), e4 = __expf(p4 - mx);
        float inv = 1.0f / (e0 + e1 + e2 + e3 + e4);
        if (bl < valid) {
            float* op = out + (size_t)pvals[bl]*35 + q*5;
            op[0] = e0*inv; op[1] = e1*inv; op[2] = e2*inv; op[3] = e3*inv; op[4] = e4*inv;
        }
    }
}

// ---------------- the single kernel ----------------
__global__ __launch_bounds__(256) void CalibrationNetwork_81329500717524_kernel(
    const void* xraw, const int* __restrict__ jid,
    const void* W1v, const void* W1av, const void* W2v, const void* W2av,
    const void* Vv,  const void* Vav, float* __restrict__ out)
{
    __shared__ unsigned short z1L[112 * Z_STRIDE];   // 30464 B
    __shared__ unsigned short z2A[112 * Z_STRIDE];   // 30464 B (A1 then z2)
    __shared__ float lg[112 * 8];                    // 3584 B
    __shared__ int pvals[16];
    __shared__ int wq[4][12];                        // per-wave-quarter judge counts
    __shared__ int flags[2];                         // isb, j64

    const int tid = threadIdx.x;
    const int l = tid & 63, w = tid >> 6;
    const int quad = l >> 4, m = l & 15;

    // ---- dtype probes (wave 0) ----
    if (tid < 64) {
        unsigned wb = ((const unsigned*)W1v)[tid];
        unsigned lo = wb & 0xFFFFu, e = (lo >> 7) & 0xFFu;
        unsigned long long mb = __ballot(lo == 0u || (e >= 100u && e <= 130u));
        unsigned long long mo = __ballot(jid[2*tid + 1] != 0);
        if (tid == 0) { flags[0] = (__popcll(mb) >= 32); flags[1] = (mo == 0ULL); }
    }
    __syncthreads();
    const int isb = flags[0], j64 = flags[1];

    // ---- pass A: wave w counts judges in its contiguous quarter ----
    {
        int c[12];
        #pragma unroll
        for (int jj = 0; jj < 12; ++jj) c[jj] = 0;
        const int base = w * 4096;
        #pragma unroll 1
        for (int it = 0; it < 64; ++it) {
            int idx = base + it*64 + l;
            int j = j64 ? jid[2*idx] : jid[idx];
            #pragma unroll
            for (int jj = 0; jj < 12; ++jj) {
                unsigned long long mk = __ballot(j == jj);
                c[jj] += (int)__popcll(mk);
            }
        }
        if (l == 0) {
            #pragma unroll
            for (int jj = 0; jj < 12; ++jj) wq[w][jj] = c[jj];
        }
    }
    __syncthreads();

    // block-uniform counts + this wave's prefix
    int cntR[12];
    #pragma unroll
    for (int jj = 0; jj < 12; ++jj)
        cntR[jj] = wq[0][jj] + wq[1][jj] + wq[2][jj] + wq[3][jj];
    int totTiles = 0;
    #pragma unroll
    for (int jj = 0; jj < 12; ++jj) totTiles += (cntR[jj] + 15) >> 4;

    // ---- persistent tile loop ----
    #pragma unroll 1
    for (int v = blockIdx.x; v < totTiles; v += GRID_MAIN) {
        // locate judge/tile (register-only, constant-indexed)
        int jT = 0, tT = 0, cj = 0, acc = 0;
        #pragma unroll
        for (int jj = 0; jj < 12; ++jj) {
            int c = cntR[jj], nt = (c + 15) >> 4;
            if (v >= acc && v < acc + nt) { jT = jj; tT = v - acc; cj = c; }
            acc += nt;
        }
        const int valid = min(16, cj - tT*16);
        const int wbase = tT * 16;

        __syncthreads();                 // previous tile fully consumed
        if (tid < 16) pvals[tid] = 0;    // safe default b-index
        __syncthreads();

        // ---- pass B: each wave re-scans its quarter, emits window ranks ----
        {
            int wpre = 0;                // matches of jT before this wave's quarter
            if (w > 0) wpre += wq[0][jT];
            if (w > 1) wpre += wq[1][jT];
            if (w > 2) wpre += wq[2][jT];
            int wcnt = wq[w][jT];
            if (wpre < wbase + 16 && wpre + wcnt > wbase) {
                int run = wpre;
                const int base = w * 4096;
                #pragma unroll 1
                for (int it = 0; it < 64; ++it) {
                    if (run >= wbase + 16) break;          // wave-uniform
                    int idx = base + it*64 + l;
                    int j = j64 ? jid[2*idx] : jid[idx];
                    unsigned long long mk = __ballot(j == jT);
                    int cnt = (int)__popcll(mk);
                    if (run + cnt > wbase) {
                        if (j == jT) {
                            int r = run + (int)__popcll(mk & ((1ULL << l) - 1ULL));
                            int s = r - wbase;
                            if (s >= 0 && s < 16) pvals[s] = idx;
                        }
                    }
                    run += cnt;
                }
            }
        }
        __syncthreads();

        // ---- compute (verified MFMA pipeline) ----
        if (isb) do_tile((const __hip_bfloat16*)xraw,
            (const __hip_bfloat16*)W1v, (const __hip_bfloat16*)W1av,
            (const __hip_bfloat16*)W2v, (const __hip_bfloat16*)W2av,
            (const __hip_bfloat16*)Vv,  (const __hip_bfloat16*)Vav,
            out, z1L, z2A, lg, pvals, jT, valid, tid, l, w, quad, m);
        else do_tile((const float*)xraw,
            (const float*)W1v, (const float*)W1av,
            (const float*)W2v, (const float*)W2av,
            (const float*)Vv,  (const float*)Vav,
            out, z1L, z2A, lg, pvals, jT, valid, tid, l, w, quad, m);
    }
}

extern "C" void kernel_launch(void* const* d_in, const int* in_sizes, int n_in,
                              void* d_out, int out_size, void* d_ws, size_t ws_size,
                              hipStream_t stream)
{
    const void* x   = d_in[0];
    const int*  jid = (const int*)d_in[1];
    const void* W1  = d_in[2];
    const void* W1a = d_in[3];
    const void* W2  = d_in[4];
    const void* W2a = d_in[5];
    const void* V   = d_in[6];
    const void* Va  = d_in[7];
    float* out = (float*)d_out;

    // ONE dispatch: no workspace, no pre-kernels, no atomics.
    CalibrationNetwork_81329500717524_kernel<<<GRID_MAIN, 256, 0, stream>>>(
        x, jid, W1, W1a, W2, W2a, V, Va, out);
}

// Round 11
// 166.268 us; speedup vs baseline: 1.4344x; 1.4344x over previous
//
#include <hip/hip_runtime.h>
#include <hip/hip_bf16.h>

// Problem: B=16384, J=12, Q=7, O=5, H1=H2=128.  Output: fp32 [B,Q,O].
// R11 = R9 (verified 3-dispatch MFMA pipeline) with the memset+atomic scatter
// replaced by a deterministic single-block scatter (R10-verified logic)
// => 2 dispatches total.
#define B_TOT 16384
#define NQ 7
#define NO 5

typedef float v4f __attribute__((ext_vector_type(4)));
typedef _Float16 v8h __attribute__((ext_vector_type(8)));

// ---------------- workspace layout (u32 slots) ----------------
//  W1F: [12][ks2][nt8][lane64][jj8] f16 : layer-1 B (k = q*6+i, K padded 42->64)
//  W2F: [12][ks4][nt8][lane64][jj8] f16 : layer-2 B (k = i' 0..127)
//  V3F: [12][q7][ks4][lane64][jj8]  f16 : layer-3 B (n<5 valid)
//  W2L: [12][128] f32   : W2c row i'=128 (fixup)
//  V3L: [12][7][16] f32 : Vc row i'=128 (cols 5..15 = 0)
//  PERM: [12][16384] fixed per-judge regions
//  CNT : [12] final counts (written by scatter block, no atomics)
#define WS_W1F  0
#define WS_W2F  (WS_W1F + 49152)
#define WS_V3F  (WS_W2F + 98304)
#define WS_W2L  (WS_V3F + 86016)
#define WS_V3L  (WS_W2L + 1536)
#define WS_PERM (WS_V3L + 1344)
#define WS_CNT  (WS_PERM + 12*16384)
#define WS_ISB  (WS_CNT + 12)
#define WS_TOT_U32 (WS_ISB + 1)
#define WS_NEEDED_BYTES ((size_t)WS_TOT_U32 * 4)

#define CFRAG_TOT (49152 + 98304 + 86016 + 1536 + 1344)   // 236352
#define NBLK_COMBINE ((CFRAG_TOT + 255) / 256)            // 924
#define NBLK_PRE (NBLK_COMBINE + 1)                       // 925 (last = scatter)

// ---------------- helpers ----------------
__device__ __forceinline__ float ldf(const float* p) { return *p; }
__device__ __forceinline__ float ldf(const __hip_bfloat16* p) { return __bfloat162float(*p); }
__device__ __forceinline__ float sigmoidf_(float v) { return 1.0f / (1.0f + __expf(-v)); }
__device__ __forceinline__ unsigned short f2h(float f) {
    _Float16 h = (_Float16)f; return __builtin_bit_cast(unsigned short, h);
}
__device__ __forceinline__ float h2f(unsigned short u) {
    return (float)__builtin_bit_cast(_Float16, u);
}
__device__ __forceinline__ unsigned pack2(float a, float b) {
    return (unsigned)f2h(a) | ((unsigned)f2h(b) << 16);
}
__device__ __forceinline__ v8h bc8h(uint4 u) { return __builtin_bit_cast(v8h, u); }

// ---------------- probes (fallback path) ----------------
__device__ __forceinline__ int probe_is_bf16(const unsigned int* w1bits) {
    int hits = 0;
    for (int t = 0; t < 64; ++t) {
        unsigned lo = w1bits[t] & 0xFFFFu, e = (lo >> 7) & 0xFFu;
        if (lo == 0u || (e >= 100u && e <= 130u)) ++hits;
    }
    return hits >= 32;
}
__device__ __forceinline__ int probe_is_j64(const int* jid) {
    int o = 0;
    for (int t = 0; t < 64; ++t) o |= jid[2*t + 1];
    return (o == 0) ? 1 : 0;
}

// ---------------- combine body (R8/R9-verified) ----------------
template<typename T>
__device__ __forceinline__ void combine_body(
    int idx, const T* W1, const T* W1a, const T* W2, const T* W2a,
    const T* V, const T* Va, unsigned* ws32, float* wsF)
{
    if (idx < 49152) {                               // W1F
        int p = idx & 3, l = (idx >> 2) & 63, nt = (idx >> 8) & 7,
            ks = (idx >> 11) & 1, j = idx >> 12;
        int n = nt*16 + (l & 15);
        float v[2];
        #pragma unroll
        for (int s = 0; s < 2; ++s) {
            int k = ks*32 + ((l >> 4) << 3) + 2*p + s;
            v[s] = (k < 42) ? (ldf(W1 + k*128 + n) + ldf(W1a + j*5376 + k*128 + n)) : 0.0f;
        }
        ws32[WS_W1F + idx] = pack2(v[0], v[1]);
    } else if (idx < 49152 + 98304) {                // W2F
        int t = idx - 49152;
        int p = t & 3, l = (t >> 2) & 63, nt = (t >> 8) & 7,
            ks = (t >> 11) & 3, j = t >> 13;
        int n = nt*16 + (l & 15);
        float v[2];
        #pragma unroll
        for (int s = 0; s < 2; ++s) {
            int k = ks*32 + ((l >> 4) << 3) + 2*p + s;
            v[s] = ldf(W2 + k*128 + n) + ldf(W2a + (j*129 + k)*128 + n);
        }
        ws32[WS_W2F + t] = pack2(v[0], v[1]);
    } else if (idx < 49152 + 98304 + 86016) {        // V3F
        int t = idx - (49152 + 98304);
        int p = t & 3, l = (t >> 2) & 63, ks = (t >> 8) & 3;
        int jq = t >> 10, q = jq % 7, j = jq / 7;
        int n = l & 15;
        float v[2];
        #pragma unroll
        for (int s = 0; s < 2; ++s) {
            int k = ks*32 + ((l >> 4) << 3) + 2*p + s;
            v[s] = (n < 5) ? (ldf(V + q*645 + k*5 + n) + ldf(Va + j*4515 + q*645 + k*5 + n))
                           : 0.0f;
        }
        ws32[WS_V3F + t] = pack2(v[0], v[1]);
    } else if (idx < 49152 + 98304 + 86016 + 1536) { // W2L
        int t = idx - (49152 + 98304 + 86016);
        int j = t >> 7, n = t & 127;
        wsF[WS_W2L + t] = ldf(W2 + 128*128 + n) + ldf(W2a + (j*129 + 128)*128 + n);
    } else if (idx < CFRAG_TOT) {                    // V3L
        int t = idx - (49152 + 98304 + 86016 + 1536);
        int c = t & 15, jq = t >> 4, q = jq % 7, j = jq / 7;
        wsF[WS_V3L + t] = (c < 5)
            ? (ldf(V + q*645 + 640 + c) + ldf(Va + j*4515 + q*645 + 640 + c)) : 0.0f;
    }
}

// ---------------- fused pre: combine (0..923) + deterministic scatter (924) --
__global__ __launch_bounds__(256) void fused_pre_kernel(
    const void* W1, const void* W1a, const void* W2, const void* W2a,
    const void* V,  const void* Va,  const int* jid, unsigned* ws32)
{
    __shared__ int sflag;
    __shared__ int wq[4][12];
    const int tid = threadIdx.x;
    int* wsI = (int*)ws32;

    if ((int)blockIdx.x < NBLK_COMBINE) {
        // ---- combine: per-block inline isb probe ----
        if (tid < 64) {
            unsigned wb = ((const unsigned*)W1)[tid];
            unsigned lo = wb & 0xFFFFu, e = (lo >> 7) & 0xFFu;
            unsigned long long mb = __ballot(lo == 0u || (e >= 100u && e <= 130u));
            if (tid == 0) sflag = (__popcll(mb) >= 32);
        }
        __syncthreads();
        const int isb = sflag;
        int idx = blockIdx.x * 256 + tid;
        if (idx >= CFRAG_TOT) return;
        float* wsF = (float*)ws32;
        if (isb) combine_body(idx,
            (const __hip_bfloat16*)W1, (const __hip_bfloat16*)W1a,
            (const __hip_bfloat16*)W2, (const __hip_bfloat16*)W2a,
            (const __hip_bfloat16*)V,  (const __hip_bfloat16*)Va, ws32, wsF);
        else combine_body(idx,
            (const float*)W1, (const float*)W1a, (const float*)W2,
            (const float*)W2a, (const float*)V, (const float*)Va, ws32, wsF);
    } else {
        // ---- deterministic scatter: single block, no atomics (R10-verified) --
        const int l = tid & 63, w = tid >> 6;
        if (tid < 64) {
            unsigned long long mo = __ballot(jid[2*tid + 1] != 0);
            unsigned wb = ((const unsigned*)W1)[tid];
            unsigned lo = wb & 0xFFFFu, e = (lo >> 7) & 0xFFu;
            unsigned long long mb = __ballot(lo == 0u || (e >= 100u && e <= 130u));
            if (tid == 0) {
                sflag = (mo == 0ULL);
                wsI[WS_ISB] = (__popcll(mb) >= 32);
            }
        }
        __syncthreads();
        const int j64 = sflag;
        const int base = w * 4096;

        // pass A: per-wave-quarter judge histogram
        int c[12];
        #pragma unroll
        for (int jj = 0; jj < 12; ++jj) c[jj] = 0;
        #pragma unroll 1
        for (int it = 0; it < 64; ++it) {
            int idx = base + it*64 + l;
            int j = j64 ? jid[2*idx] : jid[idx];
            #pragma unroll
            for (int jj = 0; jj < 12; ++jj)
                c[jj] += (int)__popcll(__ballot(j == jj));
        }
        if (l == 0) {
            #pragma unroll
            for (int jj = 0; jj < 12; ++jj) wq[w][jj] = c[jj];
        }
        __syncthreads();

        // per-wave running ranks start at the prefix over earlier waves
        int run[12];
        #pragma unroll
        for (int jj = 0; jj < 12; ++jj) {
            int s = 0;
            if (w > 0) s += wq[0][jj];
            if (w > 1) s += wq[1][jj];
            if (w > 2) s += wq[2][jj];
            run[jj] = s;
        }
        // pass B: re-scan, write exact ranks (unique addresses, no atomics)
        #pragma unroll 1
        for (int it = 0; it < 64; ++it) {
            int idx = base + it*64 + l;
            int j = j64 ? jid[2*idx] : jid[idx];
            #pragma unroll
            for (int jj = 0; jj < 12; ++jj) {
                unsigned long long mk = __ballot(j == jj);
                if (mk) {
                    if (j == jj) {
                        int r = run[jj] + (int)__popcll(mk & ((1ULL << l) - 1ULL));
                        wsI[WS_PERM + jj*16384 + r] = idx;
                    }
                    run[jj] += (int)__popcll(mk);
                }
            }
        }
        __syncthreads();
        if (tid < 12)
            wsI[WS_CNT + tid] = wq[0][tid] + wq[1][tid] + wq[2][tid] + wq[3][tid];
    }
}

// ---------------- main MFMA kernel (persistent, grid 512; R9-verified) -------
#define Z_STRIDE 136   // u16 row stride (16B-aligned rows)
#define A_STRIDE 72
__global__ __launch_bounds__(256) void CalibrationNetwork_81329500717524_kernel(
    const void* xraw, const unsigned* __restrict__ ws32, float* __restrict__ out)
{
    __shared__ unsigned short z1L[112 * Z_STRIDE];
    __shared__ unsigned short z2A[112 * Z_STRIDE];   // A1 during L1, z2 after
    __shared__ float lg[112 * 8];
    __shared__ int pvals[16];

    const int* wsI = (const int*)ws32;
    const int tid = threadIdx.x;
    const int l = tid & 63, w = tid >> 6;
    const int quad = l >> 4, m = l & 15;
    const int isb = wsI[WS_ISB];

    int cntR[12];
    #pragma unroll
    for (int jj = 0; jj < 12; ++jj) cntR[jj] = wsI[WS_CNT + jj];
    int totTiles = 0;
    #pragma unroll
    for (int jj = 0; jj < 12; ++jj) totTiles += (cntR[jj] + 15) >> 4;

    #pragma unroll 1
    for (int v = blockIdx.x; v < totTiles; v += gridDim.x) {
        int jT = 0, tT = 0, cj = 0, acc = 0;
        #pragma unroll
        for (int jj = 0; jj < 12; ++jj) {
            int c = cntR[jj], nt = (c + 15) >> 4;
            if (v >= acc && v < acc + nt) { jT = jj; tT = v - acc; cj = c; }
            acc += nt;
        }
        const int valid = min(16, cj - tT*16);
        const int start = jT*16384 + tT*16;

        __syncthreads();   // previous tile fully consumed

        // ---- staging A ----
        {
            unsigned* a32 = (unsigned*)z2A;
            for (int i = tid; i < 112 * A_STRIDE / 2; i += 256) a32[i] = 0u;
            if (tid < 112) z1L[tid * Z_STRIDE] = 0x3C00;   // 1.0h
            if (tid < 16) {
                int bl = tid < valid ? tid : valid - 1;
                pvals[tid] = wsI[WS_PERM + start + bl];
            }
        }
        __syncthreads();
        // ---- staging B: A1 rows {1, x0..x4} at col q*6 ----
        if (tid < 112) {
            int bl = tid / 7, q = tid - bl*7;
            int bg = pvals[bl];
            float x0, x1, x2, x3, x4;
            if (isb) {
                const __hip_bfloat16* xp = (const __hip_bfloat16*)xraw + bg*35 + q*5;
                x0 = ldf(xp); x1 = ldf(xp+1); x2 = ldf(xp+2); x3 = ldf(xp+3); x4 = ldf(xp+4);
            } else {
                const float* xp = (const float*)xraw + bg*35 + q*5;
                x0 = xp[0]; x1 = xp[1]; x2 = xp[2]; x3 = xp[3]; x4 = xp[4];
            }
            unsigned* rp = (unsigned*)&z2A[tid * A_STRIDE + q*6];
            rp[0] = 0x3C00u | ((unsigned)f2h(x0) << 16);
            rp[1] = pack2(x1, x2);
            rp[2] = pack2(x3, x4);
        }
        __syncthreads();

        // ---- layer 1: [112 x 64] x [64 x 128] ----
        {
            const uint4* BF = (const uint4*)(ws32 + WS_W1F) + jT*1024;
            #pragma unroll
            for (int nt2 = 0; nt2 < 2; ++nt2) {
                const int nt = w*2 + nt2;
                const uint4 b0 = BF[(0*8 + nt)*64 + l];
                const uint4 b1 = BF[(1*8 + nt)*64 + l];
                #pragma unroll 1
                for (int mt = 0; mt < 7; ++mt) {
                    const uint4 a0 = *(const uint4*)&z2A[(mt*16 + m)*A_STRIDE + quad*8];
                    const uint4 a1 = *(const uint4*)&z2A[(mt*16 + m)*A_STRIDE + 32 + quad*8];
                    v4f acc2 = {0.f, 0.f, 0.f, 0.f};
                    acc2 = __builtin_amdgcn_mfma_f32_16x16x32_f16(bc8h(a0), bc8h(b0), acc2, 0, 0, 0);
                    acc2 = __builtin_amdgcn_mfma_f32_16x16x32_f16(bc8h(a1), bc8h(b1), acc2, 0, 0, 0);
                    const int col = nt*16 + m;
                    #pragma unroll
                    for (int i = 0; i < 4; ++i) {
                        int row = mt*16 + quad*4 + i;
                        z1L[row*Z_STRIDE + 1 + col] = f2h(sigmoidf_(acc2[i]));
                    }
                }
            }
        }
        __syncthreads();

        // ---- layer 2: [112 x 128] x [128 x 128] + i'=128 fixup ----
        {
            if (tid < 112) z2A[tid * Z_STRIDE] = 0x3C00;   // z2 bias col
            const uint4* BF = (const uint4*)(ws32 + WS_W2F) + jT*2048;
            const float* w2l = (const float*)ws32 + WS_W2L + jT*128;
            #pragma unroll
            for (int nt2 = 0; nt2 < 2; ++nt2) {
                const int nt = w*2 + nt2;
                uint4 Bv[4];
                #pragma unroll
                for (int ks = 0; ks < 4; ++ks) Bv[ks] = BF[(ks*8 + nt)*64 + l];
                const float wl = w2l[nt*16 + m];
                #pragma unroll 1
                for (int mt = 0; mt < 7; ++mt) {
                    v4f acc2 = {0.f, 0.f, 0.f, 0.f};
                    #pragma unroll
                    for (int ks = 0; ks < 4; ++ks) {
                        const uint4 a = *(const uint4*)&z1L[(mt*16 + m)*Z_STRIDE + ks*32 + quad*8];
                        acc2 = __builtin_amdgcn_mfma_f32_16x16x32_f16(bc8h(a), bc8h(Bv[ks]), acc2, 0, 0, 0);
                    }
                    const int col = nt*16 + m;
                    #pragma unroll
                    for (int i = 0; i < 4; ++i) {
                        int row = mt*16 + quad*4 + i;
                        float zl = h2f(z1L[row*Z_STRIDE + 128]);   // z1[h=127]
                        float vv = acc2[i] + zl * wl;
                        z2A[row*Z_STRIDE + 1 + col] = f2h(sigmoidf_(vv));
                    }
                }
            }
        }
        __syncthreads();

        // ---- layer 3: per q [16 x 128] x [128 x 16(5)] + fixup -> logits ----
        {
            const uint4* BF = (const uint4*)(ws32 + WS_V3F) + jT*7*256;
            const float* v3l = (const float*)ws32 + WS_V3L + jT*7*16;
            #pragma unroll 1
            for (int qi = 0; qi < 2; ++qi) {
                const int q = w + qi*4;
                if (q > 6) break;
                v4f acc2 = {0.f, 0.f, 0.f, 0.f};
                #pragma unroll
                for (int ks = 0; ks < 4; ++ks) {
                    const uint4 b = BF[q*256 + ks*64 + l];
                    const uint4 a = *(const uint4*)&z2A[(m*7 + q)*Z_STRIDE + ks*32 + quad*8];
                    acc2 = __builtin_amdgcn_mfma_f32_16x16x32_f16(bc8h(a), bc8h(b), acc2, 0, 0, 0);
                }
                const float vl = v3l[q*16 + m];
                #pragma unroll
                for (int i = 0; i < 4; ++i) {
                    int bloc = quad*4 + i;
                    float zl = h2f(z2A[(bloc*7 + q)*Z_STRIDE + 128]);  // z2[h'=127]
                    float logit = acc2[i] + zl * vl;
                    if (m < 5) lg[(bloc*7 + q)*8 + m] = logit;
                }
            }
        }
        __syncthreads();

        // ---- softmax + store ----
        if (tid < 112) {
            int bl = tid / 7, q = tid - bl*7;
            const float* pr = &lg[tid*8];
            float p0 = pr[0], p1 = pr[1], p2 = pr[2], p3 = pr[3], p4 = pr[4];
            float mx = fmaxf(fmaxf(fmaxf(p0, p1), fmaxf(p2, p3)), p4);
            float e0 = __expf(p0 - mx), e1 = __expf(p1 - mx), e2 = __expf(p2 - mx),
                  e3 = __expf(p3 - mx), e4 = __expf(p4 - mx);
            float inv = 1.0f / (e0 + e1 + e2 + e3 + e4);
            if (bl < valid) {
                float* op = out + (size_t)pvals[bl]*35 + q*5;
                op[0] = e0*inv; op[1] = e1*inv; op[2] = e2*inv; op[3] = e3*inv; op[4] = e4*inv;
            }
        }
    }
}

// ---------------- fallback path B: no workspace ----------------
template<typename T>
__device__ void direct_body(
    const T* __restrict__ x, const int* __restrict__ jid, int j64,
    const T* __restrict__ W1, const T* __restrict__ W1a,
    const T* __restrict__ W2, const T* __restrict__ W2a,
    const T* __restrict__ V,  const T* __restrict__ Va,
    float* __restrict__ out, float (*lds_z1)[NQ][128])
{
    const int tid = threadIdx.x;
    const int l = tid & 63, w = tid >> 6;
    #pragma unroll 1
    for (int t = 0; t < 4; ++t) {
        const int b = blockIdx.x * 16 + w * 4 + t;
        const int j = j64 ? jid[2*b] : jid[b];
        float xv = 0.0f;
        if (l < 35) xv = ldf(x + b*35 + l);
        #pragma unroll
        for (int q = 0; q < NQ; ++q) {
            const T* Wq  = W1  + q*768;
            const T* Waq = W1a + j*5376 + q*768;
            float a  = ldf(Wq + l)      + ldf(Waq + l);
            float bb = ldf(Wq + 64 + l) + ldf(Waq + 64 + l);
            #pragma unroll
            for (int i = 1; i <= 5; ++i) {
                float xi = __shfl(xv, q*5 + (i - 1), 64);
                a  = fmaf(xi, ldf(Wq + i*128 + l)      + ldf(Waq + i*128 + l),      a);
                bb = fmaf(xi, ldf(Wq + i*128 + 64 + l) + ldf(Waq + i*128 + 64 + l), bb);
            }
            lds_z1[w][q][l]      = sigmoidf_(a);
            lds_z1[w][q][64 + l] = sigmoidf_(bb);
        }
        __syncthreads();
        float accA[NQ], accB[NQ];
        {
            const float biasA = ldf(W2 + l)      + ldf(W2a + j*129*128 + l);
            const float biasB = ldf(W2 + 64 + l) + ldf(W2a + j*129*128 + 64 + l);
            #pragma unroll
            for (int q = 0; q < NQ; ++q) { accA[q] = biasA; accB[q] = biasB; }
        }
        #pragma unroll 1
        for (int k = 0; k < 128; ++k) {
            const int i = k + 1;
            const float wA = ldf(W2 + i*128 + l)      + ldf(W2a + (j*129 + i)*128 + l);
            const float wB = ldf(W2 + i*128 + 64 + l) + ldf(W2a + (j*129 + i)*128 + 64 + l);
            #pragma unroll
            for (int q = 0; q < NQ; ++q) {
                const float z = lds_z1[w][q][k];
                accA[q] = fmaf(wA, z, accA[q]);
                accB[q] = fmaf(wB, z, accB[q]);
            }
        }
        __syncthreads();
        #pragma unroll 1
        for (int q = 0; q < NQ; ++q) {
            const float zA = sigmoidf_(accA[q]);
            const float zB = sigmoidf_(accB[q]);
            const T* Vq  = V  + q*645;
            const T* Vaq = Va + j*4515 + q*645;
            float p[NO];
            #pragma unroll
            for (int o = 0; o < NO; ++o) {
                float vA = ldf(Vq + (1 + l)*5 + o)  + ldf(Vaq + (1 + l)*5 + o);
                float vB = ldf(Vq + (65 + l)*5 + o) + ldf(Vaq + (65 + l)*5 + o);
                p[o] = zA*vA + zB*vB;
            }
            #pragma unroll
            for (int off = 32; off > 0; off >>= 1) {
                #pragma unroll
                for (int o = 0; o < NO; ++o) p[o] += __shfl_xor(p[o], off, 64);
            }
            #pragma unroll
            for (int o = 0; o < NO; ++o) p[o] += ldf(Vq + o) + ldf(Vaq + o);
            float mx = fmaxf(fmaxf(fmaxf(p[0], p[1]), fmaxf(p[2], p[3])), p[4]);
            float e[NO], s = 0.0f;
            #pragma unroll
            for (int o = 0; o < NO; ++o) { e[o] = __expf(p[o] - mx); s += e[o]; }
            float inv = 1.0f / s;
            if (l < 5) out[b*35 + q*5 + l] = e[l] * inv;
        }
    }
}

__global__ __launch_bounds__(256) void calib_direct_kernel(
    const void* x, const int* jid,
    const void* W1, const void* W1a, const void* W2, const void* W2a,
    const void* V,  const void* Va, float* out)
{
    __shared__ __align__(16) float lds_z1[4][NQ][128];
    const int isb = probe_is_bf16((const unsigned int*)W1);
    const int j64 = probe_is_j64(jid);
    if (isb) direct_body(
        (const __hip_bfloat16*)x, jid, j64,
        (const __hip_bfloat16*)W1, (const __hip_bfloat16*)W1a,
        (const __hip_bfloat16*)W2, (const __hip_bfloat16*)W2a,
        (const __hip_bfloat16*)V,  (const __hip_bfloat16*)Va, out, lds_z1);
    else direct_body(
        (const float*)x, jid, j64,
        (const float*)W1, (const float*)W1a, (const float*)W2,
        (const float*)W2a, (const float*)V, (const float*)Va, out, lds_z1);
}

extern "C" void kernel_launch(void* const* d_in, const int* in_sizes, int n_in,
                              void* d_out, int out_size, void* d_ws, size_t ws_size,
                              hipStream_t stream)
{
    const void* x   = d_in[0];
    const int*  jid = (const int*)d_in[1];
    const void* W1  = d_in[2];
    const void* W1a = d_in[3];
    const void* W2  = d_in[4];
    const void* W2a = d_in[5];
    const void* V   = d_in[6];
    const void* Va  = d_in[7];
    float* out = (float*)d_out;

    if (ws_size >= WS_NEEDED_BYTES) {
        unsigned* ws32 = (unsigned*)d_ws;
        // 2 dispatches: fused combine + deterministic scatter, then main.
        fused_pre_kernel<<<NBLK_PRE, 256, 0, stream>>>(
            W1, W1a, W2, W2a, V, Va, jid, ws32);
        CalibrationNetwork_81329500717524_kernel<<<512, 256, 0, stream>>>(
            x, ws32, out);
    } else {
        calib_direct_kernel<<<B_TOT / 16, 256, 0, stream>>>(
            x, jid, W1, W1a, W2, W2a, V, Va, out);
    }
}

// Round 12
// 146.101 us; speedup vs baseline: 1.6324x; 1.1380x over previous
//
#include <hip/hip_runtime.h>
#include <hip/hip_bf16.h>

// Problem: B=16384, J=12, Q=7, O=5, H1=H2=128.  Output: fp32 [B,Q,O].
// R12 = R11 with the scatter block's serial-latency loop replaced by
// register-chunked loads (16 independent loads per vmcnt wait).
#define B_TOT 16384
#define NQ 7
#define NO 5

typedef float v4f __attribute__((ext_vector_type(4)));
typedef _Float16 v8h __attribute__((ext_vector_type(8)));

// ---------------- workspace layout (u32 slots) ----------------
#define WS_W1F  0
#define WS_W2F  (WS_W1F + 49152)
#define WS_V3F  (WS_W2F + 98304)
#define WS_W2L  (WS_V3F + 86016)
#define WS_V3L  (WS_W2L + 1536)
#define WS_PERM (WS_V3L + 1344)
#define WS_CNT  (WS_PERM + 12*16384)
#define WS_ISB  (WS_CNT + 12)
#define WS_TOT_U32 (WS_ISB + 1)
#define WS_NEEDED_BYTES ((size_t)WS_TOT_U32 * 4)

#define CFRAG_TOT (49152 + 98304 + 86016 + 1536 + 1344)   // 236352
#define NBLK_COMBINE ((CFRAG_TOT + 255) / 256)            // 924
#define NBLK_PRE (NBLK_COMBINE + 1)                       // 925 (last = scatter)

// ---------------- helpers ----------------
__device__ __forceinline__ float ldf(const float* p) { return *p; }
__device__ __forceinline__ float ldf(const __hip_bfloat16* p) { return __bfloat162float(*p); }
__device__ __forceinline__ float sigmoidf_(float v) { return 1.0f / (1.0f + __expf(-v)); }
__device__ __forceinline__ unsigned short f2h(float f) {
    _Float16 h = (_Float16)f; return __builtin_bit_cast(unsigned short, h);
}
__device__ __forceinline__ float h2f(unsigned short u) {
    return (float)__builtin_bit_cast(_Float16, u);
}
__device__ __forceinline__ unsigned pack2(float a, float b) {
    return (unsigned)f2h(a) | ((unsigned)f2h(b) << 16);
}
__device__ __forceinline__ v8h bc8h(uint4 u) { return __builtin_bit_cast(v8h, u); }

// ---------------- probes (fallback path) ----------------
__device__ __forceinline__ int probe_is_bf16(const unsigned int* w1bits) {
    int hits = 0;
    for (int t = 0; t < 64; ++t) {
        unsigned lo = w1bits[t] & 0xFFFFu, e = (lo >> 7) & 0xFFu;
        if (lo == 0u || (e >= 100u && e <= 130u)) ++hits;
    }
    return hits >= 32;
}
__device__ __forceinline__ int probe_is_j64(const int* jid) {
    int o = 0;
    for (int t = 0; t < 64; ++t) o |= jid[2*t + 1];
    return (o == 0) ? 1 : 0;
}

// ---------------- combine body (R8/R9-verified) ----------------
template<typename T>
__device__ __forceinline__ void combine_body(
    int idx, const T* W1, const T* W1a, const T* W2, const T* W2a,
    const T* V, const T* Va, unsigned* ws32, float* wsF)
{
    if (idx < 49152) {                               // W1F
        int p = idx & 3, l = (idx >> 2) & 63, nt = (idx >> 8) & 7,
            ks = (idx >> 11) & 1, j = idx >> 12;
        int n = nt*16 + (l & 15);
        float v[2];
        #pragma unroll
        for (int s = 0; s < 2; ++s) {
            int k = ks*32 + ((l >> 4) << 3) + 2*p + s;
            v[s] = (k < 42) ? (ldf(W1 + k*128 + n) + ldf(W1a + j*5376 + k*128 + n)) : 0.0f;
        }
        ws32[WS_W1F + idx] = pack2(v[0], v[1]);
    } else if (idx < 49152 + 98304) {                // W2F
        int t = idx - 49152;
        int p = t & 3, l = (t >> 2) & 63, nt = (t >> 8) & 7,
            ks = (t >> 11) & 3, j = t >> 13;
        int n = nt*16 + (l & 15);
        float v[2];
        #pragma unroll
        for (int s = 0; s < 2; ++s) {
            int k = ks*32 + ((l >> 4) << 3) + 2*p + s;
            v[s] = ldf(W2 + k*128 + n) + ldf(W2a + (j*129 + k)*128 + n);
        }
        ws32[WS_W2F + t] = pack2(v[0], v[1]);
    } else if (idx < 49152 + 98304 + 86016) {        // V3F
        int t = idx - (49152 + 98304);
        int p = t & 3, l = (t >> 2) & 63, ks = (t >> 8) & 3;
        int jq = t >> 10, q = jq % 7, j = jq / 7;
        int n = l & 15;
        float v[2];
        #pragma unroll
        for (int s = 0; s < 2; ++s) {
            int k = ks*32 + ((l >> 4) << 3) + 2*p + s;
            v[s] = (n < 5) ? (ldf(V + q*645 + k*5 + n) + ldf(Va + j*4515 + q*645 + k*5 + n))
                           : 0.0f;
        }
        ws32[WS_V3F + t] = pack2(v[0], v[1]);
    } else if (idx < 49152 + 98304 + 86016 + 1536) { // W2L
        int t = idx - (49152 + 98304 + 86016);
        int j = t >> 7, n = t & 127;
        wsF[WS_W2L + t] = ldf(W2 + 128*128 + n) + ldf(W2a + (j*129 + 128)*128 + n);
    } else if (idx < CFRAG_TOT) {                    // V3L
        int t = idx - (49152 + 98304 + 86016 + 1536);
        int c = t & 15, jq = t >> 4, q = jq % 7, j = jq / 7;
        wsF[WS_V3L + t] = (c < 5)
            ? (ldf(V + q*645 + 640 + c) + ldf(Va + j*4515 + q*645 + 640 + c)) : 0.0f;
    }
}

// ---------------- fused pre: combine (0..923) + deterministic scatter (924) --
__global__ __launch_bounds__(256) void fused_pre_kernel(
    const void* W1, const void* W1a, const void* W2, const void* W2a,
    const void* V,  const void* Va,  const int* jid, unsigned* ws32)
{
    __shared__ int sflag;
    __shared__ int wq[4][12];
    const int tid = threadIdx.x;
    int* wsI = (int*)ws32;

    if ((int)blockIdx.x < NBLK_COMBINE) {
        // ---- combine: per-block inline isb probe ----
        if (tid < 64) {
            unsigned wb = ((const unsigned*)W1)[tid];
            unsigned lo = wb & 0xFFFFu, e = (lo >> 7) & 0xFFu;
            unsigned long long mb = __ballot(lo == 0u || (e >= 100u && e <= 130u));
            if (tid == 0) sflag = (__popcll(mb) >= 32);
        }
        __syncthreads();
        const int isb = sflag;
        int idx = blockIdx.x * 256 + tid;
        if (idx >= CFRAG_TOT) return;
        float* wsF = (float*)ws32;
        if (isb) combine_body(idx,
            (const __hip_bfloat16*)W1, (const __hip_bfloat16*)W1a,
            (const __hip_bfloat16*)W2, (const __hip_bfloat16*)W2a,
            (const __hip_bfloat16*)V,  (const __hip_bfloat16*)Va, ws32, wsF);
        else combine_body(idx,
            (const float*)W1, (const float*)W1a, (const float*)W2,
            (const float*)W2a, (const float*)V, (const float*)Va, ws32, wsF);
    } else {
        // ---- deterministic scatter, latency-hidden (chunked register loads) --
        const int l = tid & 63, w = tid >> 6;
        if (tid < 64) {
            unsigned long long mo = __ballot(jid[2*tid + 1] != 0);
            unsigned wb = ((const unsigned*)W1)[tid];
            unsigned lo = wb & 0xFFFFu, e = (lo >> 7) & 0xFFu;
            unsigned long long mb = __ballot(lo == 0u || (e >= 100u && e <= 130u));
            if (tid == 0) {
                sflag = (mo == 0ULL);
                wsI[WS_ISB] = (__popcll(mb) >= 32);
            }
        }
        __syncthreads();
        const int j64 = sflag;
        const int base = w * 4096;

        // pass A: per-wave-quarter judge histogram (16 loads in flight per wait)
        int c[12];
        #pragma unroll
        for (int jj = 0; jj < 12; ++jj) c[jj] = 0;
        #pragma unroll 1
        for (int ch = 0; ch < 4; ++ch) {
            int jv[16];
            #pragma unroll
            for (int t = 0; t < 16; ++t) {
                int idx = base + (ch*16 + t)*64 + l;
                jv[t] = j64 ? jid[2*idx] : jid[idx];
            }
            #pragma unroll
            for (int t = 0; t < 16; ++t) {
                #pragma unroll
                for (int jj = 0; jj < 12; ++jj)
                    c[jj] += (int)__popcll(__ballot(jv[t] == jj));
            }
        }
        if (l == 0) {
            #pragma unroll
            for (int jj = 0; jj < 12; ++jj) wq[w][jj] = c[jj];
        }
        __syncthreads();

        // per-wave running ranks start at the prefix over earlier waves
        int run[12];
        #pragma unroll
        for (int jj = 0; jj < 12; ++jj) {
            int s = 0;
            if (w > 0) s += wq[0][jj];
            if (w > 1) s += wq[1][jj];
            if (w > 2) s += wq[2][jj];
            run[jj] = s;
        }
        // pass B: re-scan (L2-warm), write exact ranks (unique addresses)
        #pragma unroll 1
        for (int ch = 0; ch < 4; ++ch) {
            int jv[16];
            #pragma unroll
            for (int t = 0; t < 16; ++t) {
                int idx = base + (ch*16 + t)*64 + l;
                jv[t] = j64 ? jid[2*idx] : jid[idx];
            }
            #pragma unroll
            for (int t = 0; t < 16; ++t) {
                int idx = base + (ch*16 + t)*64 + l;
                #pragma unroll
                for (int jj = 0; jj < 12; ++jj) {
                    unsigned long long mk = __ballot(jv[t] == jj);
                    if (mk) {
                        if (jv[t] == jj) {
                            int r = run[jj] + (int)__popcll(mk & ((1ULL << l) - 1ULL));
                            wsI[WS_PERM + jj*16384 + r] = idx;
                        }
                        run[jj] += (int)__popcll(mk);
                    }
                }
            }
        }
        __syncthreads();
        if (tid < 12)
            wsI[WS_CNT + tid] = wq[0][tid] + wq[1][tid] + wq[2][tid] + wq[3][tid];
    }
}

// ---------------- main MFMA kernel (persistent, grid 512; R9-verified) -------
#define Z_STRIDE 136   // u16 row stride (16B-aligned rows)
#define A_STRIDE 72
__global__ __launch_bounds__(256) void CalibrationNetwork_81329500717524_kernel(
    const void* xraw, const unsigned* __restrict__ ws32, float* __restrict__ out)
{
    __shared__ unsigned short z1L[112 * Z_STRIDE];
    __shared__ unsigned short z2A[112 * Z_STRIDE];   // A1 during L1, z2 after
    __shared__ float lg[112 * 8];
    __shared__ int pvals[16];

    const int* wsI = (const int*)ws32;
    const int tid = threadIdx.x;
    const int l = tid & 63, w = tid >> 6;
    const int quad = l >> 4, m = l & 15;
    const int isb = wsI[WS_ISB];

    int cntR[12];
    #pragma unroll
    for (int jj = 0; jj < 12; ++jj) cntR[jj] = wsI[WS_CNT + jj];
    int totTiles = 0;
    #pragma unroll
    for (int jj = 0; jj < 12; ++jj) totTiles += (cntR[jj] + 15) >> 4;

    #pragma unroll 1
    for (int v = blockIdx.x; v < totTiles; v += gridDim.x) {
        int jT = 0, tT = 0, cj = 0, acc = 0;
        #pragma unroll
        for (int jj = 0; jj < 12; ++jj) {
            int c = cntR[jj], nt = (c + 15) >> 4;
            if (v >= acc && v < acc + nt) { jT = jj; tT = v - acc; cj = c; }
            acc += nt;
        }
        const int valid = min(16, cj - tT*16);
        const int start = jT*16384 + tT*16;

        __syncthreads();   // previous tile fully consumed

        // ---- staging A ----
        {
            unsigned* a32 = (unsigned*)z2A;
            for (int i = tid; i < 112 * A_STRIDE / 2; i += 256) a32[i] = 0u;
            if (tid < 112) z1L[tid * Z_STRIDE] = 0x3C00;   // 1.0h
            if (tid < 16) {
                int bl = tid < valid ? tid : valid - 1;
                pvals[tid] = wsI[WS_PERM + start + bl];
            }
        }
        __syncthreads();
        // ---- staging B: A1 rows {1, x0..x4} at col q*6 ----
        if (tid < 112) {
            int bl = tid / 7, q = tid - bl*7;
            int bg = pvals[bl];
            float x0, x1, x2, x3, x4;
            if (isb) {
                const __hip_bfloat16* xp = (const __hip_bfloat16*)xraw + bg*35 + q*5;
                x0 = ldf(xp); x1 = ldf(xp+1); x2 = ldf(xp+2); x3 = ldf(xp+3); x4 = ldf(xp+4);
            } else {
                const float* xp = (const float*)xraw + bg*35 + q*5;
                x0 = xp[0]; x1 = xp[1]; x2 = xp[2]; x3 = xp[3]; x4 = xp[4];
            }
            unsigned* rp = (unsigned*)&z2A[tid * A_STRIDE + q*6];
            rp[0] = 0x3C00u | ((unsigned)f2h(x0) << 16);
            rp[1] = pack2(x1, x2);
            rp[2] = pack2(x3, x4);
        }
        __syncthreads();

        // ---- layer 1: [112 x 64] x [64 x 128] ----
        {
            const uint4* BF = (const uint4*)(ws32 + WS_W1F) + jT*1024;
            #pragma unroll
            for (int nt2 = 0; nt2 < 2; ++nt2) {
                const int nt = w*2 + nt2;
                const uint4 b0 = BF[(0*8 + nt)*64 + l];
                const uint4 b1 = BF[(1*8 + nt)*64 + l];
                #pragma unroll 1
                for (int mt = 0; mt < 7; ++mt) {
                    const uint4 a0 = *(const uint4*)&z2A[(mt*16 + m)*A_STRIDE + quad*8];
                    const uint4 a1 = *(const uint4*)&z2A[(mt*16 + m)*A_STRIDE + 32 + quad*8];
                    v4f acc2 = {0.f, 0.f, 0.f, 0.f};
                    acc2 = __builtin_amdgcn_mfma_f32_16x16x32_f16(bc8h(a0), bc8h(b0), acc2, 0, 0, 0);
                    acc2 = __builtin_amdgcn_mfma_f32_16x16x32_f16(bc8h(a1), bc8h(b1), acc2, 0, 0, 0);
                    const int col = nt*16 + m;
                    #pragma unroll
                    for (int i = 0; i < 4; ++i) {
                        int row = mt*16 + quad*4 + i;
                        z1L[row*Z_STRIDE + 1 + col] = f2h(sigmoidf_(acc2[i]));
                    }
                }
            }
        }
        __syncthreads();

        // ---- layer 2: [112 x 128] x [128 x 128] + i'=128 fixup ----
        {
            if (tid < 112) z2A[tid * Z_STRIDE] = 0x3C00;   // z2 bias col
            const uint4* BF = (const uint4*)(ws32 + WS_W2F) + jT*2048;
            const float* w2l = (const float*)ws32 + WS_W2L + jT*128;
            #pragma unroll
            for (int nt2 = 0; nt2 < 2; ++nt2) {
                const int nt = w*2 + nt2;
                uint4 Bv[4];
                #pragma unroll
                for (int ks = 0; ks < 4; ++ks) Bv[ks] = BF[(ks*8 + nt)*64 + l];
                const float wl = w2l[nt*16 + m];
                #pragma unroll 1
                for (int mt = 0; mt < 7; ++mt) {
                    v4f acc2 = {0.f, 0.f, 0.f, 0.f};
                    #pragma unroll
                    for (int ks = 0; ks < 4; ++ks) {
                        const uint4 a = *(const uint4*)&z1L[(mt*16 + m)*Z_STRIDE + ks*32 + quad*8];
                        acc2 = __builtin_amdgcn_mfma_f32_16x16x32_f16(bc8h(a), bc8h(Bv[ks]), acc2, 0, 0, 0);
                    }
                    const int col = nt*16 + m;
                    #pragma unroll
                    for (int i = 0; i < 4; ++i) {
                        int row = mt*16 + quad*4 + i;
                        float zl = h2f(z1L[row*Z_STRIDE + 128]);   // z1[h=127]
                        float vv = acc2[i] + zl * wl;
                        z2A[row*Z_STRIDE + 1 + col] = f2h(sigmoidf_(vv));
                    }
                }
            }
        }
        __syncthreads();

        // ---- layer 3: per q [16 x 128] x [128 x 16(5)] + fixup -> logits ----
        {
            const uint4* BF = (const uint4*)(ws32 + WS_V3F) + jT*7*256;
            const float* v3l = (const float*)ws32 + WS_V3L + jT*7*16;
            #pragma unroll 1
            for (int qi = 0; qi < 2; ++qi) {
                const int q = w + qi*4;
                if (q > 6) break;
                v4f acc2 = {0.f, 0.f, 0.f, 0.f};
                #pragma unroll
                for (int ks = 0; ks < 4; ++ks) {
                    const uint4 b = BF[q*256 + ks*64 + l];
                    const uint4 a = *(const uint4*)&z2A[(m*7 + q)*Z_STRIDE + ks*32 + quad*8];
                    acc2 = __builtin_amdgcn_mfma_f32_16x16x32_f16(bc8h(a), bc8h(b), acc2, 0, 0, 0);
                }
                const float vl = v3l[q*16 + m];
                #pragma unroll
                for (int i = 0; i < 4; ++i) {
                    int bloc = quad*4 + i;
                    float zl = h2f(z2A[(bloc*7 + q)*Z_STRIDE + 128]);  // z2[h'=127]
                    float logit = acc2[i] + zl * vl;
                    if (m < 5) lg[(bloc*7 + q)*8 + m] = logit;
                }
            }
        }
        __syncthreads();

        // ---- softmax + store ----
        if (tid < 112) {
            int bl = tid / 7, q = tid - bl*7;
            const float* pr = &lg[tid*8];
            float p0 = pr[0], p1 = pr[1], p2 = pr[2], p3 = pr[3], p4 = pr[4];
            float mx = fmaxf(fmaxf(fmaxf(p0, p1), fmaxf(p2, p3)), p4);
            float e0 = __expf(p0 - mx), e1 = __expf(p1 - mx), e2 = __expf(p2 - mx),
                  e3 = __expf(p3 - mx), e4 = __expf(p4 - mx);
            float inv = 1.0f / (e0 + e1 + e2 + e3 + e4);
            if (bl < valid) {
                float* op = out + (size_t)pvals[bl]*35 + q*5;
                op[0] = e0*inv; op[1] = e1*inv; op[2] = e2*inv; op[3] = e3*inv; op[4] = e4*inv;
            }
        }
    }
}

// ---------------- fallback path B: no workspace ----------------
template<typename T>
__device__ void direct_body(
    const T* __restrict__ x, const int* __restrict__ jid, int j64,
    const T* __restrict__ W1, const T* __restrict__ W1a,
    const T* __restrict__ W2, const T* __restrict__ W2a,
    const T* __restrict__ V,  const T* __restrict__ Va,
    float* __restrict__ out, float (*lds_z1)[NQ][128])
{
    const int tid = threadIdx.x;
    const int l = tid & 63, w = tid >> 6;
    #pragma unroll 1
    for (int t = 0; t < 4; ++t) {
        const int b = blockIdx.x * 16 + w * 4 + t;
        const int j = j64 ? jid[2*b] : jid[b];
        float xv = 0.0f;
        if (l < 35) xv = ldf(x + b*35 + l);
        #pragma unroll
        for (int q = 0; q < NQ; ++q) {
            const T* Wq  = W1  + q*768;
            const T* Waq = W1a + j*5376 + q*768;
            float a  = ldf(Wq + l)      + ldf(Waq + l);
            float bb = ldf(Wq + 64 + l) + ldf(Waq + 64 + l);
            #pragma unroll
            for (int i = 1; i <= 5; ++i) {
                float xi = __shfl(xv, q*5 + (i - 1), 64);
                a  = fmaf(xi, ldf(Wq + i*128 + l)      + ldf(Waq + i*128 + l),      a);
                bb = fmaf(xi, ldf(Wq + i*128 + 64 + l) + ldf(Waq + i*128 + 64 + l), bb);
            }
            lds_z1[w][q][l]      = sigmoidf_(a);
            lds_z1[w][q][64 + l] = sigmoidf_(bb);
        }
        __syncthreads();
        float accA[NQ], accB[NQ];
        {
            const float biasA = ldf(W2 + l)      + ldf(W2a + j*129*128 + l);
            const float biasB = ldf(W2 + 64 + l) + ldf(W2a + j*129*128 + 64 + l);
            #pragma unroll
            for (int q = 0; q < NQ; ++q) { accA[q] = biasA; accB[q] = biasB; }
        }
        #pragma unroll 1
        for (int k = 0; k < 128; ++k) {
            const int i = k + 1;
            const float wA = ldf(W2 + i*128 + l)      + ldf(W2a + (j*129 + i)*128 + l);
            const float wB = ldf(W2 + i*128 + 64 + l) + ldf(W2a + (j*129 + i)*128 + 64 + l);
            #pragma unroll
            for (int q = 0; q < NQ; ++q) {
                const float z = lds_z1[w][q][k];
                accA[q] = fmaf(wA, z, accA[q]);
                accB[q] = fmaf(wB, z, accB[q]);
            }
        }
        __syncthreads();
        #pragma unroll 1
        for (int q = 0; q < NQ; ++q) {
            const float zA = sigmoidf_(accA[q]);
            const float zB = sigmoidf_(accB[q]);
            const T* Vq  = V  + q*645;
            const T* Vaq = Va + j*4515 + q*645;
            float p[NO];
            #pragma unroll
            for (int o = 0; o < NO; ++o) {
                float vA = ldf(Vq + (1 + l)*5 + o)  + ldf(Vaq + (1 + l)*5 + o);
                float vB = ldf(Vq + (65 + l)*5 + o) + ldf(Vaq + (65 + l)*5 + o);
                p[o] = zA*vA + zB*vB;
            }
            #pragma unroll
            for (int off = 32; off > 0; off >>= 1) {
                #pragma unroll
                for (int o = 0; o < NO; ++o) p[o] += __shfl_xor(p[o], off, 64);
            }
            #pragma unroll
            for (int o = 0; o < NO; ++o) p[o] += ldf(Vq + o) + ldf(Vaq + o);
            float mx = fmaxf(fmaxf(fmaxf(p[0], p[1]), fmaxf(p[2], p[3])), p[4]);
            float e[NO], s = 0.0f;
            #pragma unroll
            for (int o = 0; o < NO; ++o) { e[o] = __expf(p[o] - mx); s += e[o]; }
            float inv = 1.0f / s;
            if (l < 5) out[b*35 + q*5 + l] = e[l] * inv;
        }
    }
}

__global__ __launch_bounds__(256) void calib_direct_kernel(
    const void* x, const int* jid,
    const void* W1, const void* W1a, const void* W2, const void* W2a,
    const void* V,  const void* Va, float* out)
{
    __shared__ __align__(16) float lds_z1[4][NQ][128];
    const int isb = probe_is_bf16((const unsigned int*)W1);
    const int j64 = probe_is_j64(jid);
    if (isb) direct_body(
        (const __hip_bfloat16*)x, jid, j64,
        (const __hip_bfloat16*)W1, (const __hip_bfloat16*)W1a,
        (const __hip_bfloat16*)W2, (const __hip_bfloat16*)W2a,
        (const __hip_bfloat16*)V,  (const __hip_bfloat16*)Va, out, lds_z1);
    else direct_body(
        (const float*)x, jid, j64,
        (const float*)W1, (const float*)W1a, (const float*)W2,
        (const float*)W2a, (const float*)V, (const float*)Va, out, lds_z1);
}

extern "C" void kernel_launch(void* const* d_in, const int* in_sizes, int n_in,
                              void* d_out, int out_size, void* d_ws, size_t ws_size,
                              hipStream_t stream)
{
    const void* x   = d_in[0];
    const int*  jid = (const int*)d_in[1];
    const void* W1  = d_in[2];
    const void* W1a = d_in[3];
    const void* W2  = d_in[4];
    const void* W2a = d_in[5];
    const void* V   = d_in[6];
    const void* Va  = d_in[7];
    float* out = (float*)d_out;

    if (ws_size >= WS_NEEDED_BYTES) {
        unsigned* ws32 = (unsigned*)d_ws;
        // 2 dispatches: fused combine + deterministic scatter, then main.
        fused_pre_kernel<<<NBLK_PRE, 256, 0, stream>>>(
            W1, W1a, W2, W2a, V, Va, jid, ws32);
        CalibrationNetwork_81329500717524_kernel<<<512, 256, 0, stream>>>(
            x, ws32, out);
    } else {
        calib_direct_kernel<<<B_TOT / 16, 256, 0, stream>>>(
            x, jid, W1, W1a, W2, W2a, V, Va, out);
    }
}

// Round 13
// 112.360 us; speedup vs baseline: 2.1226x; 1.3003x over previous
//
#include <hip/hip_runtime.h>
#include <hip/hip_bf16.h>

// Problem: B=16384, J=12, Q=7, O=5, H1=H2=128.  Output: fp32 [B,Q,O].
// R13: 2 dispatches. fused_pre = combine (924 blocks) + PARALLEL no-init
// scatter (64 blocks, 1 elem/thread, fragmented per-block perm regions +
// histograms; no atomics, no memset). Main kernel rebuilds global order from
// the 64x12 histogram via an LDS prefix table.
#define B_TOT 16384
#define NQ 7
#define NO 5

typedef float v4f __attribute__((ext_vector_type(4)));
typedef _Float16 v8h __attribute__((ext_vector_type(8)));

// ---------------- workspace layout (u32 slots) ----------------
#define WS_W1F  0
#define WS_W2F  (WS_W1F + 49152)
#define WS_V3F  (WS_W2F + 98304)
#define WS_W2L  (WS_V3F + 86016)
#define WS_V3L  (WS_W2L + 1536)
#define WS_PERM (WS_V3L + 1344)          // [12][16384], fragment at sblk*256
#define WS_HIST (WS_PERM + 12*16384)     // [64][12]
#define WS_ISB  (WS_HIST + 768)
#define WS_TOT_U32 (WS_ISB + 1)
#define WS_NEEDED_BYTES ((size_t)WS_TOT_U32 * 4)

#define CFRAG_TOT (49152 + 98304 + 86016 + 1536 + 1344)   // 236352
#define NBLK_COMBINE ((CFRAG_TOT + 255) / 256)            // 924
#define NBLK_SCATTER 64
#define NBLK_PRE (NBLK_COMBINE + NBLK_SCATTER)            // 988

// ---------------- helpers ----------------
__device__ __forceinline__ float ldf(const float* p) { return *p; }
__device__ __forceinline__ float ldf(const __hip_bfloat16* p) { return __bfloat162float(*p); }
__device__ __forceinline__ float sigmoidf_(float v) { return 1.0f / (1.0f + __expf(-v)); }
__device__ __forceinline__ unsigned short f2h(float f) {
    _Float16 h = (_Float16)f; return __builtin_bit_cast(unsigned short, h);
}
__device__ __forceinline__ float h2f(unsigned short u) {
    return (float)__builtin_bit_cast(_Float16, u);
}
__device__ __forceinline__ unsigned pack2(float a, float b) {
    return (unsigned)f2h(a) | ((unsigned)f2h(b) << 16);
}
__device__ __forceinline__ v8h bc8h(uint4 u) { return __builtin_bit_cast(v8h, u); }

// ---------------- probes (fallback path) ----------------
__device__ __forceinline__ int probe_is_bf16(const unsigned int* w1bits) {
    int hits = 0;
    for (int t = 0; t < 64; ++t) {
        unsigned lo = w1bits[t] & 0xFFFFu, e = (lo >> 7) & 0xFFu;
        if (lo == 0u || (e >= 100u && e <= 130u)) ++hits;
    }
    return hits >= 32;
}
__device__ __forceinline__ int probe_is_j64(const int* jid) {
    int o = 0;
    for (int t = 0; t < 64; ++t) o |= jid[2*t + 1];
    return (o == 0) ? 1 : 0;
}

// ---------------- combine body (R8/R9-verified) ----------------
template<typename T>
__device__ __forceinline__ void combine_body(
    int idx, const T* W1, const T* W1a, const T* W2, const T* W2a,
    const T* V, const T* Va, unsigned* ws32, float* wsF)
{
    if (idx < 49152) {                               // W1F
        int p = idx & 3, l = (idx >> 2) & 63, nt = (idx >> 8) & 7,
            ks = (idx >> 11) & 1, j = idx >> 12;
        int n = nt*16 + (l & 15);
        float v[2];
        #pragma unroll
        for (int s = 0; s < 2; ++s) {
            int k = ks*32 + ((l >> 4) << 3) + 2*p + s;
            v[s] = (k < 42) ? (ldf(W1 + k*128 + n) + ldf(W1a + j*5376 + k*128 + n)) : 0.0f;
        }
        ws32[WS_W1F + idx] = pack2(v[0], v[1]);
    } else if (idx < 49152 + 98304) {                // W2F
        int t = idx - 49152;
        int p = t & 3, l = (t >> 2) & 63, nt = (t >> 8) & 7,
            ks = (t >> 11) & 3, j = t >> 13;
        int n = nt*16 + (l & 15);
        float v[2];
        #pragma unroll
        for (int s = 0; s < 2; ++s) {
            int k = ks*32 + ((l >> 4) << 3) + 2*p + s;
            v[s] = ldf(W2 + k*128 + n) + ldf(W2a + (j*129 + k)*128 + n);
        }
        ws32[WS_W2F + t] = pack2(v[0], v[1]);
    } else if (idx < 49152 + 98304 + 86016) {        // V3F
        int t = idx - (49152 + 98304);
        int p = t & 3, l = (t >> 2) & 63, ks = (t >> 8) & 3;
        int jq = t >> 10, q = jq % 7, j = jq / 7;
        int n = l & 15;
        float v[2];
        #pragma unroll
        for (int s = 0; s < 2; ++s) {
            int k = ks*32 + ((l >> 4) << 3) + 2*p + s;
            v[s] = (n < 5) ? (ldf(V + q*645 + k*5 + n) + ldf(Va + j*4515 + q*645 + k*5 + n))
                           : 0.0f;
        }
        ws32[WS_V3F + t] = pack2(v[0], v[1]);
    } else if (idx < 49152 + 98304 + 86016 + 1536) { // W2L
        int t = idx - (49152 + 98304 + 86016);
        int j = t >> 7, n = t & 127;
        wsF[WS_W2L + t] = ldf(W2 + 128*128 + n) + ldf(W2a + (j*129 + 128)*128 + n);
    } else if (idx < CFRAG_TOT) {                    // V3L
        int t = idx - (49152 + 98304 + 86016 + 1536);
        int c = t & 15, jq = t >> 4, q = jq % 7, j = jq / 7;
        wsF[WS_V3L + t] = (c < 5)
            ? (ldf(V + q*645 + 640 + c) + ldf(Va + j*4515 + q*645 + 640 + c)) : 0.0f;
    }
}

// ---------------- fused pre: combine (0..923) + parallel scatter (924..987) --
__global__ __launch_bounds__(256) void fused_pre_kernel(
    const void* W1, const void* W1a, const void* W2, const void* W2a,
    const void* V,  const void* Va,  const int* jid, unsigned* ws32)
{
    __shared__ int sflag;
    __shared__ int wq[4][12];
    const int tid = threadIdx.x;
    int* wsI = (int*)ws32;

    if ((int)blockIdx.x < NBLK_COMBINE) {
        // ---- combine: per-block inline isb probe ----
        if (tid < 64) {
            unsigned wb = ((const unsigned*)W1)[tid];
            unsigned lo = wb & 0xFFFFu, e = (lo >> 7) & 0xFFu;
            unsigned long long mb = __ballot(lo == 0u || (e >= 100u && e <= 130u));
            if (tid == 0) sflag = (__popcll(mb) >= 32);
        }
        __syncthreads();
        const int isb = sflag;
        int idx = blockIdx.x * 256 + tid;
        if (idx >= CFRAG_TOT) return;
        float* wsF = (float*)ws32;
        if (isb) combine_body(idx,
            (const __hip_bfloat16*)W1, (const __hip_bfloat16*)W1a,
            (const __hip_bfloat16*)W2, (const __hip_bfloat16*)W2a,
            (const __hip_bfloat16*)V,  (const __hip_bfloat16*)Va, ws32, wsF);
        else combine_body(idx,
            (const float*)W1, (const float*)W1a, (const float*)W2,
            (const float*)W2a, (const float*)V, (const float*)Va, ws32, wsF);
    } else {
        // ---- parallel no-init scatter: 1 element per thread ----
        const int sblk = blockIdx.x - NBLK_COMBINE;   // 0..63
        const int l = tid & 63, w = tid >> 6;
        if (sblk == 0 && tid < 64) {                  // publish isb once
            unsigned wb = ((const unsigned*)W1)[tid];
            unsigned lo = wb & 0xFFFFu, e = (lo >> 7) & 0xFFu;
            unsigned long long mb = __ballot(lo == 0u || (e >= 100u && e <= 130u));
            if (tid == 0) wsI[WS_ISB] = (__popcll(mb) >= 32);
        }
        if (tid < 64) {
            unsigned long long mo = __ballot(jid[2*tid + 1] != 0);
            if (tid == 0) sflag = (mo == 0ULL);
        }
        __syncthreads();
        const int j64 = sflag;
        const int idx = sblk * 256 + tid;
        const int j = j64 ? jid[2*idx] : jid[idx];

        // one ballot round: per-wave histogram + in-wave rank
        int rloc = 0;
        int c[12];
        #pragma unroll
        for (int jj = 0; jj < 12; ++jj) {
            unsigned long long mk = __ballot(j == jj);
            c[jj] = (int)__popcll(mk);
            if (j == jj) rloc = (int)__popcll(mk & ((1ULL << l) - 1ULL));
        }
        if (l == 0) {
            #pragma unroll
            for (int jj = 0; jj < 12; ++jj) wq[w][jj] = c[jj];
        }
        __syncthreads();
        int pre = 0;
        #pragma unroll
        for (int w2 = 0; w2 < 4; ++w2)
            if (w2 < w) pre += wq[w2][j];
        wsI[WS_PERM + j*16384 + sblk*256 + pre + rloc] = idx;   // unique addr
        if (tid < 12)
            wsI[WS_HIST + sblk*12 + tid] =
                wq[0][tid] + wq[1][tid] + wq[2][tid] + wq[3][tid];
    }
}

// ---------------- main MFMA kernel (persistent, grid 512; R9-verified core) --
#define Z_STRIDE 136   // u16 row stride (16B-aligned rows)
#define A_STRIDE 72
__global__ __launch_bounds__(256) void CalibrationNetwork_81329500717524_kernel(
    const void* xraw, const unsigned* __restrict__ ws32, float* __restrict__ out)
{
    __shared__ __align__(16) unsigned short z1L[112 * Z_STRIDE];  // 30464 B
    __shared__ __align__(16) unsigned short z2A[112 * Z_STRIDE];  // 30464 B
    __shared__ int pref[12 * 65];                                 // 3120 B
    __shared__ int pvals[16];
    float* lg = (float*)z1L;          // logits alias: z1L dead after layer 2
    int* histL = (int*)z2A;           // startup alias: z2A dead before staging

    const int* wsI = (const int*)ws32;
    const int tid = threadIdx.x;
    const int l = tid & 63, w = tid >> 6;
    const int quad = l >> 4, m = l & 15;
    const int isb = wsI[WS_ISB];

    // ---- startup: load 64x12 histogram, build per-judge block-prefix ----
    for (int i = tid; i < 768; i += 256) histL[i] = wsI[WS_HIST + i];
    __syncthreads();
    if (tid < 12) {
        int acc = 0;
        #pragma unroll 1
        for (int k = 0; k < 64; ++k) {
            pref[tid*65 + k] = acc;
            acc += histL[k*12 + tid];
        }
        pref[tid*65 + 64] = acc;      // = cnt[judge tid]
    }
    __syncthreads();
    int cntR[12];
    #pragma unroll
    for (int jj = 0; jj < 12; ++jj) cntR[jj] = pref[jj*65 + 64];
    int totTiles = 0;
    #pragma unroll
    for (int jj = 0; jj < 12; ++jj) totTiles += (cntR[jj] + 15) >> 4;

    #pragma unroll 1
    for (int v = blockIdx.x; v < totTiles; v += gridDim.x) {
        int jT = 0, tT = 0, cj = 0, acc = 0;
        #pragma unroll
        for (int jj = 0; jj < 12; ++jj) {
            int c = cntR[jj], nt = (c + 15) >> 4;
            if (v >= acc && v < acc + nt) { jT = jj; tT = v - acc; cj = c; }
            acc += nt;
        }
        const int valid = min(16, cj - tT*16);

        __syncthreads();   // previous tile fully consumed

        // ---- staging A: zero A1, z1L bias col, perm lookup via prefix ----
        {
            unsigned* a32 = (unsigned*)z2A;
            for (int i = tid; i < 112 * A_STRIDE / 2; i += 256) a32[i] = 0u;
            if (tid < 112) z1L[tid * Z_STRIDE] = 0x3C00;   // 1.0h
            if (tid < 16) {
                int bl = tid < valid ? tid : valid - 1;
                int r = tT*16 + bl;                         // global rank in judge jT
                int k = 0;
                #pragma unroll 1
                for (int kk = 1; kk < 64; ++kk)
                    if (pref[jT*65 + kk] <= r) k = kk;
                pvals[tid] = wsI[WS_PERM + jT*16384 + k*256 + (r - pref[jT*65 + k])];
            }
        }
        __syncthreads();
        // ---- staging B: A1 rows {1, x0..x4} at col q*6 ----
        if (tid < 112) {
            int bl = tid / 7, q = tid - bl*7;
            int bg = pvals[bl];
            float x0, x1, x2, x3, x4;
            if (isb) {
                const __hip_bfloat16* xp = (const __hip_bfloat16*)xraw + bg*35 + q*5;
                x0 = ldf(xp); x1 = ldf(xp+1); x2 = ldf(xp+2); x3 = ldf(xp+3); x4 = ldf(xp+4);
            } else {
                const float* xp = (const float*)xraw + bg*35 + q*5;
                x0 = xp[0]; x1 = xp[1]; x2 = xp[2]; x3 = xp[3]; x4 = xp[4];
            }
            unsigned* rp = (unsigned*)&z2A[tid * A_STRIDE + q*6];
            rp[0] = 0x3C00u | ((unsigned)f2h(x0) << 16);
            rp[1] = pack2(x1, x2);
            rp[2] = pack2(x3, x4);
        }
        __syncthreads();

        // ---- layer 1: [112 x 64] x [64 x 128] ----
        {
            const uint4* BF = (const uint4*)(ws32 + WS_W1F) + jT*1024;
            #pragma unroll
            for (int nt2 = 0; nt2 < 2; ++nt2) {
                const int nt = w*2 + nt2;
                const uint4 b0 = BF[(0*8 + nt)*64 + l];
                const uint4 b1 = BF[(1*8 + nt)*64 + l];
                #pragma unroll 1
                for (int mt = 0; mt < 7; ++mt) {
                    const uint4 a0 = *(const uint4*)&z2A[(mt*16 + m)*A_STRIDE + quad*8];
                    const uint4 a1 = *(const uint4*)&z2A[(mt*16 + m)*A_STRIDE + 32 + quad*8];
                    v4f acc2 = {0.f, 0.f, 0.f, 0.f};
                    acc2 = __builtin_amdgcn_mfma_f32_16x16x32_f16(bc8h(a0), bc8h(b0), acc2, 0, 0, 0);
                    acc2 = __builtin_amdgcn_mfma_f32_16x16x32_f16(bc8h(a1), bc8h(b1), acc2, 0, 0, 0);
                    const int col = nt*16 + m;
                    #pragma unroll
                    for (int i = 0; i < 4; ++i) {
                        int row = mt*16 + quad*4 + i;
                        z1L[row*Z_STRIDE + 1 + col] = f2h(sigmoidf_(acc2[i]));
                    }
                }
            }
        }
        __syncthreads();

        // ---- layer 2: [112 x 128] x [128 x 128] + i'=128 fixup ----
        {
            if (tid < 112) z2A[tid * Z_STRIDE] = 0x3C00;   // z2 bias col
            const uint4* BF = (const uint4*)(ws32 + WS_W2F) + jT*2048;
            const float* w2l = (const float*)ws32 + WS_W2L + jT*128;
            #pragma unroll
            for (int nt2 = 0; nt2 < 2; ++nt2) {
                const int nt = w*2 + nt2;
                uint4 Bv[4];
                #pragma unroll
                for (int ks = 0; ks < 4; ++ks) Bv[ks] = BF[(ks*8 + nt)*64 + l];
                const float wl = w2l[nt*16 + m];
                #pragma unroll 1
                for (int mt = 0; mt < 7; ++mt) {
                    v4f acc2 = {0.f, 0.f, 0.f, 0.f};
                    #pragma unroll
                    for (int ks = 0; ks < 4; ++ks) {
                        const uint4 a = *(const uint4*)&z1L[(mt*16 + m)*Z_STRIDE + ks*32 + quad*8];
                        acc2 = __builtin_amdgcn_mfma_f32_16x16x32_f16(bc8h(a), bc8h(Bv[ks]), acc2, 0, 0, 0);
                    }
                    const int col = nt*16 + m;
                    #pragma unroll
                    for (int i = 0; i < 4; ++i) {
                        int row = mt*16 + quad*4 + i;
                        float zl = h2f(z1L[row*Z_STRIDE + 128]);   // z1[h=127]
                        float vv = acc2[i] + zl * wl;
                        z2A[row*Z_STRIDE + 1 + col] = f2h(sigmoidf_(vv));
                    }
                }
            }
        }
        __syncthreads();

        // ---- layer 3: per q [16 x 128] x [128 x 16(5)] + fixup -> logits ----
        // NOTE: writes lg alias into z1L space (z1L is dead here).
        {
            const uint4* BF = (const uint4*)(ws32 + WS_V3F) + jT*7*256;
            const float* v3l = (const float*)ws32 + WS_V3L + jT*7*16;
            #pragma unroll 1
            for (int qi = 0; qi < 2; ++qi) {
                const int q = w + qi*4;
                if (q > 6) break;
                v4f acc2 = {0.f, 0.f, 0.f, 0.f};
                #pragma unroll
                for (int ks = 0; ks < 4; ++ks) {
                    const uint4 b = BF[q*256 + ks*64 + l];
                    const uint4 a = *(const uint4*)&z2A[(m*7 + q)*Z_STRIDE + ks*32 + quad*8];
                    acc2 = __builtin_amdgcn_mfma_f32_16x16x32_f16(bc8h(a), bc8h(b), acc2, 0, 0, 0);
                }
                const float vl = v3l[q*16 + m];
                #pragma unroll
                for (int i = 0; i < 4; ++i) {
                    int bloc = quad*4 + i;
                    float zl = h2f(z2A[(bloc*7 + q)*Z_STRIDE + 128]);  // z2[h'=127]
                    float logit = acc2[i] + zl * vl;
                    if (m < 5) lg[(bloc*7 + q)*8 + m] = logit;
                }
            }
        }
        __syncthreads();

        // ---- softmax + store ----
        if (tid < 112) {
            int bl = tid / 7, q = tid - bl*7;
            const float* pr = &lg[tid*8];
            float p0 = pr[0], p1 = pr[1], p2 = pr[2], p3 = pr[3], p4 = pr[4];
            float mx = fmaxf(fmaxf(fmaxf(p0, p1), fmaxf(p2, p3)), p4);
            float e0 = __expf(p0 - mx), e1 = __expf(p1 - mx), e2 = __expf(p2 - mx),
                  e3 = __expf(p3 - mx), e4 = __expf(p4 - mx);
            float inv = 1.0f / (e0 + e1 + e2 + e3 + e4);
            if (bl < valid) {
                float* op = out + (size_t)pvals[bl]*35 + q*5;
                op[0] = e0*inv; op[1] = e1*inv; op[2] = e2*inv; op[3] = e3*inv; op[4] = e4*inv;
            }
        }
    }
}

// ---------------- fallback path B: no workspace ----------------
template<typename T>
__device__ void direct_body(
    const T* __restrict__ x, const int* __restrict__ jid, int j64,
    const T* __restrict__ W1, const T* __restrict__ W1a,
    const T* __restrict__ W2, const T* __restrict__ W2a,
    const T* __restrict__ V,  const T* __restrict__ Va,
    float* __restrict__ out, float (*lds_z1)[NQ][128])
{
    const int tid = threadIdx.x;
    const int l = tid & 63, w = tid >> 6;
    #pragma unroll 1
    for (int t = 0; t < 4; ++t) {
        const int b = blockIdx.x * 16 + w * 4 + t;
        const int j = j64 ? jid[2*b] : jid[b];
        float xv = 0.0f;
        if (l < 35) xv = ldf(x + b*35 + l);
        #pragma unroll
        for (int q = 0; q < NQ; ++q) {
            const T* Wq  = W1  + q*768;
            const T* Waq = W1a + j*5376 + q*768;
            float a  = ldf(Wq + l)      + ldf(Waq + l);
            float bb = ldf(Wq + 64 + l) + ldf(Waq + 64 + l);
            #pragma unroll
            for (int i = 1; i <= 5; ++i) {
                float xi = __shfl(xv, q*5 + (i - 1), 64);
                a  = fmaf(xi, ldf(Wq + i*128 + l)      + ldf(Waq + i*128 + l),      a);
                bb = fmaf(xi, ldf(Wq + i*128 + 64 + l) + ldf(Waq + i*128 + 64 + l), bb);
            }
            lds_z1[w][q][l]      = sigmoidf_(a);
            lds_z1[w][q][64 + l] = sigmoidf_(bb);
        }
        __syncthreads();
        float accA[NQ], accB[NQ];
        {
            const float biasA = ldf(W2 + l)      + ldf(W2a + j*129*128 + l);
            const float biasB = ldf(W2 + 64 + l) + ldf(W2a + j*129*128 + 64 + l);
            #pragma unroll
            for (int q = 0; q < NQ; ++q) { accA[q] = biasA; accB[q] = biasB; }
        }
        #pragma unroll 1
        for (int k = 0; k < 128; ++k) {
            const int i = k + 1;
            const float wA = ldf(W2 + i*128 + l)      + ldf(W2a + (j*129 + i)*128 + l);
            const float wB = ldf(W2 + i*128 + 64 + l) + ldf(W2a + (j*129 + i)*128 + 64 + l);
            #pragma unroll
            for (int q = 0; q < NQ; ++q) {
                const float z = lds_z1[w][q][k];
                accA[q] = fmaf(wA, z, accA[q]);
                accB[q] = fmaf(wB, z, accB[q]);
            }
        }
        __syncthreads();
        #pragma unroll 1
        for (int q = 0; q < NQ; ++q) {
            const float zA = sigmoidf_(accA[q]);
            const float zB = sigmoidf_(accB[q]);
            const T* Vq  = V  + q*645;
            const T* Vaq = Va + j*4515 + q*645;
            float p[NO];
            #pragma unroll
            for (int o = 0; o < NO; ++o) {
                float vA = ldf(Vq + (1 + l)*5 + o)  + ldf(Vaq + (1 + l)*5 + o);
                float vB = ldf(Vq + (65 + l)*5 + o) + ldf(Vaq + (65 + l)*5 + o);
                p[o] = zA*vA + zB*vB;
            }
            #pragma unroll
            for (int off = 32; off > 0; off >>= 1) {
                #pragma unroll
                for (int o = 0; o < NO; ++o) p[o] += __shfl_xor(p[o], off, 64);
            }
            #pragma unroll
            for (int o = 0; o < NO; ++o) p[o] += ldf(Vq + o) + ldf(Vaq + o);
            float mx = fmaxf(fmaxf(fmaxf(p[0], p[1]), fmaxf(p[2], p[3])), p[4]);
            float e[NO], s = 0.0f;
            #pragma unroll
            for (int o = 0; o < NO; ++o) { e[o] = __expf(p[o] - mx); s += e[o]; }
            float inv = 1.0f / s;
            if (l < 5) out[b*35 + q*5 + l] = e[l] * inv;
        }
    }
}

__global__ __launch_bounds__(256) void calib_direct_kernel(
    const void* x, const int* jid,
    const void* W1, const void* W1a, const void* W2, const void* W2a,
    const void* V,  const void* Va, float* out)
{
    __shared__ __align__(16) float lds_z1[4][NQ][128];
    const int isb = probe_is_bf16((const unsigned int*)W1);
    const int j64 = probe_is_j64(jid);
    if (isb) direct_body(
        (const __hip_bfloat16*)x, jid, j64,
        (const __hip_bfloat16*)W1, (const __hip_bfloat16*)W1a,
        (const __hip_bfloat16*)W2, (const __hip_bfloat16*)W2a,
        (const __hip_bfloat16*)V,  (const __hip_bfloat16*)Va, out, lds_z1);
    else direct_body(
        (const float*)x, jid, j64,
        (const float*)W1, (const float*)W1a, (const float*)W2,
        (const float*)W2a, (const float*)V, (const float*)Va, out, lds_z1);
}

extern "C" void kernel_launch(void* const* d_in, const int* in_sizes, int n_in,
                              void* d_out, int out_size, void* d_ws, size_t ws_size,
                              hipStream_t stream)
{
    const void* x   = d_in[0];
    const int*  jid = (const int*)d_in[1];
    const void* W1  = d_in[2];
    const void* W1a = d_in[3];
    const void* W2  = d_in[4];
    const void* W2a = d_in[5];
    const void* V   = d_in[6];
    const void* Va  = d_in[7];
    float* out = (float*)d_out;

    if (ws_size >= WS_NEEDED_BYTES) {
        unsigned* ws32 = (unsigned*)d_ws;
        // 2 dispatches: combine + parallel no-init scatter, then main.
        fused_pre_kernel<<<NBLK_PRE, 256, 0, stream>>>(
            W1, W1a, W2, W2a, V, Va, jid, ws32);
        CalibrationNetwork_81329500717524_kernel<<<512, 256, 0, stream>>>(
            x, ws32, out);
    } else {
        calib_direct_kernel<<<B_TOT / 16, 256, 0, stream>>>(
            x, jid, W1, W1a, W2, W2a, V, Va, out);
    }
}

// Round 14
// 107.299 us; speedup vs baseline: 2.2227x; 1.0472x over previous
//
#include <hip/hip_runtime.h>
#include <hip/hip_bf16.h>

// Problem: B=16384, J=12, Q=7, O=5, H1=H2=128.  Output: fp32 [B,Q,O].
// R14 = R13 with latency fixes: wave-parallel prefix build (shfl_up),
// unrolled (MLP-friendly) perm lookup, vectorized LDS zeroing.
#define B_TOT 16384
#define NQ 7
#define NO 5

typedef float v4f __attribute__((ext_vector_type(4)));
typedef _Float16 v8h __attribute__((ext_vector_type(8)));

// ---------------- workspace layout (u32 slots) ----------------
#define WS_W1F  0
#define WS_W2F  (WS_W1F + 49152)
#define WS_V3F  (WS_W2F + 98304)
#define WS_W2L  (WS_V3F + 86016)
#define WS_V3L  (WS_W2L + 1536)
#define WS_PERM (WS_V3L + 1344)          // [12][16384], fragment at sblk*256
#define WS_HIST (WS_PERM + 12*16384)     // [64][12]
#define WS_ISB  (WS_HIST + 768)
#define WS_TOT_U32 (WS_ISB + 1)
#define WS_NEEDED_BYTES ((size_t)WS_TOT_U32 * 4)

#define CFRAG_TOT (49152 + 98304 + 86016 + 1536 + 1344)   // 236352
#define NBLK_COMBINE ((CFRAG_TOT + 255) / 256)            // 924
#define NBLK_SCATTER 64
#define NBLK_PRE (NBLK_COMBINE + NBLK_SCATTER)            // 988

// ---------------- helpers ----------------
__device__ __forceinline__ float ldf(const float* p) { return *p; }
__device__ __forceinline__ float ldf(const __hip_bfloat16* p) { return __bfloat162float(*p); }
__device__ __forceinline__ float sigmoidf_(float v) { return 1.0f / (1.0f + __expf(-v)); }
__device__ __forceinline__ unsigned short f2h(float f) {
    _Float16 h = (_Float16)f; return __builtin_bit_cast(unsigned short, h);
}
__device__ __forceinline__ float h2f(unsigned short u) {
    return (float)__builtin_bit_cast(_Float16, u);
}
__device__ __forceinline__ unsigned pack2(float a, float b) {
    return (unsigned)f2h(a) | ((unsigned)f2h(b) << 16);
}
__device__ __forceinline__ v8h bc8h(uint4 u) { return __builtin_bit_cast(v8h, u); }

// ---------------- probes (fallback path) ----------------
__device__ __forceinline__ int probe_is_bf16(const unsigned int* w1bits) {
    int hits = 0;
    for (int t = 0; t < 64; ++t) {
        unsigned lo = w1bits[t] & 0xFFFFu, e = (lo >> 7) & 0xFFu;
        if (lo == 0u || (e >= 100u && e <= 130u)) ++hits;
    }
    return hits >= 32;
}
__device__ __forceinline__ int probe_is_j64(const int* jid) {
    int o = 0;
    for (int t = 0; t < 64; ++t) o |= jid[2*t + 1];
    return (o == 0) ? 1 : 0;
}

// ---------------- combine body (R8/R9-verified) ----------------
template<typename T>
__device__ __forceinline__ void combine_body(
    int idx, const T* W1, const T* W1a, const T* W2, const T* W2a,
    const T* V, const T* Va, unsigned* ws32, float* wsF)
{
    if (idx < 49152) {                               // W1F
        int p = idx & 3, l = (idx >> 2) & 63, nt = (idx >> 8) & 7,
            ks = (idx >> 11) & 1, j = idx >> 12;
        int n = nt*16 + (l & 15);
        float v[2];
        #pragma unroll
        for (int s = 0; s < 2; ++s) {
            int k = ks*32 + ((l >> 4) << 3) + 2*p + s;
            v[s] = (k < 42) ? (ldf(W1 + k*128 + n) + ldf(W1a + j*5376 + k*128 + n)) : 0.0f;
        }
        ws32[WS_W1F + idx] = pack2(v[0], v[1]);
    } else if (idx < 49152 + 98304) {                // W2F
        int t = idx - 49152;
        int p = t & 3, l = (t >> 2) & 63, nt = (t >> 8) & 7,
            ks = (t >> 11) & 3, j = t >> 13;
        int n = nt*16 + (l & 15);
        float v[2];
        #pragma unroll
        for (int s = 0; s < 2; ++s) {
            int k = ks*32 + ((l >> 4) << 3) + 2*p + s;
            v[s] = ldf(W2 + k*128 + n) + ldf(W2a + (j*129 + k)*128 + n);
        }
        ws32[WS_W2F + t] = pack2(v[0], v[1]);
    } else if (idx < 49152 + 98304 + 86016) {        // V3F
        int t = idx - (49152 + 98304);
        int p = t & 3, l = (t >> 2) & 63, ks = (t >> 8) & 3;
        int jq = t >> 10, q = jq % 7, j = jq / 7;
        int n = l & 15;
        float v[2];
        #pragma unroll
        for (int s = 0; s < 2; ++s) {
            int k = ks*32 + ((l >> 4) << 3) + 2*p + s;
            v[s] = (n < 5) ? (ldf(V + q*645 + k*5 + n) + ldf(Va + j*4515 + q*645 + k*5 + n))
                           : 0.0f;
        }
        ws32[WS_V3F + t] = pack2(v[0], v[1]);
    } else if (idx < 49152 + 98304 + 86016 + 1536) { // W2L
        int t = idx - (49152 + 98304 + 86016);
        int j = t >> 7, n = t & 127;
        wsF[WS_W2L + t] = ldf(W2 + 128*128 + n) + ldf(W2a + (j*129 + 128)*128 + n);
    } else if (idx < CFRAG_TOT) {                    // V3L
        int t = idx - (49152 + 98304 + 86016 + 1536);
        int c = t & 15, jq = t >> 4, q = jq % 7, j = jq / 7;
        wsF[WS_V3L + t] = (c < 5)
            ? (ldf(V + q*645 + 640 + c) + ldf(Va + j*4515 + q*645 + 640 + c)) : 0.0f;
    }
}

// ---------------- fused pre: combine (0..923) + parallel scatter (924..987) --
__global__ __launch_bounds__(256) void fused_pre_kernel(
    const void* W1, const void* W1a, const void* W2, const void* W2a,
    const void* V,  const void* Va,  const int* jid, unsigned* ws32)
{
    __shared__ int sflag;
    __shared__ int wq[4][12];
    const int tid = threadIdx.x;
    int* wsI = (int*)ws32;

    if ((int)blockIdx.x < NBLK_COMBINE) {
        // ---- combine: per-block inline isb probe ----
        if (tid < 64) {
            unsigned wb = ((const unsigned*)W1)[tid];
            unsigned lo = wb & 0xFFFFu, e = (lo >> 7) & 0xFFu;
            unsigned long long mb = __ballot(lo == 0u || (e >= 100u && e <= 130u));
            if (tid == 0) sflag = (__popcll(mb) >= 32);
        }
        __syncthreads();
        const int isb = sflag;
        int idx = blockIdx.x * 256 + tid;
        if (idx >= CFRAG_TOT) return;
        float* wsF = (float*)ws32;
        if (isb) combine_body(idx,
            (const __hip_bfloat16*)W1, (const __hip_bfloat16*)W1a,
            (const __hip_bfloat16*)W2, (const __hip_bfloat16*)W2a,
            (const __hip_bfloat16*)V,  (const __hip_bfloat16*)Va, ws32, wsF);
        else combine_body(idx,
            (const float*)W1, (const float*)W1a, (const float*)W2,
            (const float*)W2a, (const float*)V, (const float*)Va, ws32, wsF);
    } else {
        // ---- parallel no-init scatter: 1 element per thread ----
        const int sblk = blockIdx.x - NBLK_COMBINE;   // 0..63
        const int l = tid & 63, w = tid >> 6;
        if (sblk == 0 && tid < 64) {                  // publish isb once
            unsigned wb = ((const unsigned*)W1)[tid];
            unsigned lo = wb & 0xFFFFu, e = (lo >> 7) & 0xFFu;
            unsigned long long mb = __ballot(lo == 0u || (e >= 100u && e <= 130u));
            if (tid == 0) wsI[WS_ISB] = (__popcll(mb) >= 32);
        }
        if (tid < 64) {
            unsigned long long mo = __ballot(jid[2*tid + 1] != 0);
            if (tid == 0) sflag = (mo == 0ULL);
        }
        __syncthreads();
        const int j64 = sflag;
        const int idx = sblk * 256 + tid;
        const int j = j64 ? jid[2*idx] : jid[idx];

        // one ballot round: per-wave histogram + in-wave rank
        int rloc = 0;
        int c[12];
        #pragma unroll
        for (int jj = 0; jj < 12; ++jj) {
            unsigned long long mk = __ballot(j == jj);
            c[jj] = (int)__popcll(mk);
            if (j == jj) rloc = (int)__popcll(mk & ((1ULL << l) - 1ULL));
        }
        if (l == 0) {
            #pragma unroll
            for (int jj = 0; jj < 12; ++jj) wq[w][jj] = c[jj];
        }
        __syncthreads();
        int pre = 0;
        #pragma unroll
        for (int w2 = 0; w2 < 4; ++w2)
            if (w2 < w) pre += wq[w2][j];
        wsI[WS_PERM + j*16384 + sblk*256 + pre + rloc] = idx;   // unique addr
        if (tid < 12)
            wsI[WS_HIST + sblk*12 + tid] =
                wq[0][tid] + wq[1][tid] + wq[2][tid] + wq[3][tid];
    }
}

// ---------------- main MFMA kernel (persistent, grid 512; R9-verified core) --
#define Z_STRIDE 136   // u16 row stride (16B-aligned rows)
#define A_STRIDE 72
__global__ __launch_bounds__(256) void CalibrationNetwork_81329500717524_kernel(
    const void* xraw, const unsigned* __restrict__ ws32, float* __restrict__ out)
{
    __shared__ __align__(16) unsigned short z1L[112 * Z_STRIDE];  // 30464 B
    __shared__ __align__(16) unsigned short z2A[112 * Z_STRIDE];  // 30464 B
    __shared__ int pref[12 * 65];                                 // 3120 B
    __shared__ int pvals[16];
    float* lg = (float*)z1L;          // logits alias: z1L dead after layer 2
    int* histL = (int*)z2A;           // startup alias: z2A dead before staging

    const int* wsI = (const int*)ws32;
    const int tid = threadIdx.x;
    const int l = tid & 63, w = tid >> 6;
    const int quad = l >> 4, m = l & 15;
    const int isb = wsI[WS_ISB];

    // ---- startup: load 64x12 histogram, wave-parallel prefix (shfl_up) ----
    for (int i = tid; i < 768; i += 256) histL[i] = wsI[WS_HIST + i];
    __syncthreads();
    // wave w owns judges 3w..3w+2; lane l holds block l's count
    #pragma unroll
    for (int jo = 0; jo < 3; ++jo) {
        const int j = w*3 + jo;
        int vc = histL[l*12 + j];
        int s = vc;
        #pragma unroll
        for (int off = 1; off < 64; off <<= 1) {
            int t = __shfl_up(s, off, 64);
            if (l >= off) s += t;
        }
        pref[j*65 + l] = s - vc;            // exclusive prefix
        if (l == 63) pref[j*65 + 64] = s;   // judge total
    }
    __syncthreads();
    int cntR[12];
    #pragma unroll
    for (int jj = 0; jj < 12; ++jj) cntR[jj] = pref[jj*65 + 64];
    int totTiles = 0;
    #pragma unroll
    for (int jj = 0; jj < 12; ++jj) totTiles += (cntR[jj] + 15) >> 4;

    #pragma unroll 1
    for (int v = blockIdx.x; v < totTiles; v += gridDim.x) {
        int jT = 0, tT = 0, cj = 0, acc = 0;
        #pragma unroll
        for (int jj = 0; jj < 12; ++jj) {
            int c = cntR[jj], nt = (c + 15) >> 4;
            if (v >= acc && v < acc + nt) { jT = jj; tT = v - acc; cj = c; }
            acc += nt;
        }
        const int valid = min(16, cj - tT*16);

        __syncthreads();   // previous tile fully consumed

        // ---- staging A: zero A1 (uint4), z1L bias col, perm lookup ----
        {
            uint4 zz; zz.x = 0; zz.y = 0; zz.z = 0; zz.w = 0;
            uint4* a128 = (uint4*)z2A;
            for (int i = tid; i < 112 * A_STRIDE / 8; i += 256) a128[i] = zz;
            if (tid < 112) z1L[tid * Z_STRIDE] = 0x3C00;   // 1.0h
            if (tid < 16) {
                int bl = tid < valid ? tid : valid - 1;
                int r = tT*16 + bl;            // global rank within judge jT
                int k = 0;
                #pragma unroll                 // independent loads -> one wait
                for (int kk = 1; kk < 64; ++kk)
                    if (pref[jT*65 + kk] <= r) k = kk;
                pvals[tid] = wsI[WS_PERM + jT*16384 + k*256 + (r - pref[jT*65 + k])];
            }
        }
        __syncthreads();
        // ---- staging B: A1 rows {1, x0..x4} at col q*6 ----
        if (tid < 112) {
            int bl = tid / 7, q = tid - bl*7;
            int bg = pvals[bl];
            float x0, x1, x2, x3, x4;
            if (isb) {
                const __hip_bfloat16* xp = (const __hip_bfloat16*)xraw + bg*35 + q*5;
                x0 = ldf(xp); x1 = ldf(xp+1); x2 = ldf(xp+2); x3 = ldf(xp+3); x4 = ldf(xp+4);
            } else {
                const float* xp = (const float*)xraw + bg*35 + q*5;
                x0 = xp[0]; x1 = xp[1]; x2 = xp[2]; x3 = xp[3]; x4 = xp[4];
            }
            unsigned* rp = (unsigned*)&z2A[tid * A_STRIDE + q*6];
            rp[0] = 0x3C00u | ((unsigned)f2h(x0) << 16);
            rp[1] = pack2(x1, x2);
            rp[2] = pack2(x3, x4);
        }
        __syncthreads();

        // ---- layer 1: [112 x 64] x [64 x 128] ----
        {
            const uint4* BF = (const uint4*)(ws32 + WS_W1F) + jT*1024;
            #pragma unroll
            for (int nt2 = 0; nt2 < 2; ++nt2) {
                const int nt = w*2 + nt2;
                const uint4 b0 = BF[(0*8 + nt)*64 + l];
                const uint4 b1 = BF[(1*8 + nt)*64 + l];
                #pragma unroll 1
                for (int mt = 0; mt < 7; ++mt) {
                    const uint4 a0 = *(const uint4*)&z2A[(mt*16 + m)*A_STRIDE + quad*8];
                    const uint4 a1 = *(const uint4*)&z2A[(mt*16 + m)*A_STRIDE + 32 + quad*8];
                    v4f acc2 = {0.f, 0.f, 0.f, 0.f};
                    acc2 = __builtin_amdgcn_mfma_f32_16x16x32_f16(bc8h(a0), bc8h(b0), acc2, 0, 0, 0);
                    acc2 = __builtin_amdgcn_mfma_f32_16x16x32_f16(bc8h(a1), bc8h(b1), acc2, 0, 0, 0);
                    const int col = nt*16 + m;
                    #pragma unroll
                    for (int i = 0; i < 4; ++i) {
                        int row = mt*16 + quad*4 + i;
                        z1L[row*Z_STRIDE + 1 + col] = f2h(sigmoidf_(acc2[i]));
                    }
                }
            }
        }
        __syncthreads();

        // ---- layer 2: [112 x 128] x [128 x 128] + i'=128 fixup ----
        {
            if (tid < 112) z2A[tid * Z_STRIDE] = 0x3C00;   // z2 bias col
            const uint4* BF = (const uint4*)(ws32 + WS_W2F) + jT*2048;
            const float* w2l = (const float*)ws32 + WS_W2L + jT*128;
            #pragma unroll
            for (int nt2 = 0; nt2 < 2; ++nt2) {
                const int nt = w*2 + nt2;
                uint4 Bv[4];
                #pragma unroll
                for (int ks = 0; ks < 4; ++ks) Bv[ks] = BF[(ks*8 + nt)*64 + l];
                const float wl = w2l[nt*16 + m];
                #pragma unroll 1
                for (int mt = 0; mt < 7; ++mt) {
                    v4f acc2 = {0.f, 0.f, 0.f, 0.f};
                    #pragma unroll
                    for (int ks = 0; ks < 4; ++ks) {
                        const uint4 a = *(const uint4*)&z1L[(mt*16 + m)*Z_STRIDE + ks*32 + quad*8];
                        acc2 = __builtin_amdgcn_mfma_f32_16x16x32_f16(bc8h(a), bc8h(Bv[ks]), acc2, 0, 0, 0);
                    }
                    const int col = nt*16 + m;
                    #pragma unroll
                    for (int i = 0; i < 4; ++i) {
                        int row = mt*16 + quad*4 + i;
                        float zl = h2f(z1L[row*Z_STRIDE + 128]);   // z1[h=127]
                        float vv = acc2[i] + zl * wl;
                        z2A[row*Z_STRIDE + 1 + col] = f2h(sigmoidf_(vv));
                    }
                }
            }
        }
        __syncthreads();

        // ---- layer 3: per q [16 x 128] x [128 x 16(5)] + fixup -> logits ----
        // writes lg alias into z1L space (z1L dead here)
        {
            const uint4* BF = (const uint4*)(ws32 + WS_V3F) + jT*7*256;
            const float* v3l = (const float*)ws32 + WS_V3L + jT*7*16;
            #pragma unroll 1
            for (int qi = 0; qi < 2; ++qi) {
                const int q = w + qi*4;
                if (q > 6) break;
                v4f acc2 = {0.f, 0.f, 0.f, 0.f};
                #pragma unroll
                for (int ks = 0; ks < 4; ++ks) {
                    const uint4 b = BF[q*256 + ks*64 + l];
                    const uint4 a = *(const uint4*)&z2A[(m*7 + q)*Z_STRIDE + ks*32 + quad*8];
                    acc2 = __builtin_amdgcn_mfma_f32_16x16x32_f16(bc8h(a), bc8h(b), acc2, 0, 0, 0);
                }
                const float vl = v3l[q*16 + m];
                #pragma unroll
                for (int i = 0; i < 4; ++i) {
                    int bloc = quad*4 + i;
                    float zl = h2f(z2A[(bloc*7 + q)*Z_STRIDE + 128]);  // z2[h'=127]
                    float logit = acc2[i] + zl * vl;
                    if (m < 5) lg[(bloc*7 + q)*8 + m] = logit;
                }
            }
        }
        __syncthreads();

        // ---- softmax + store ----
        if (tid < 112) {
            int bl = tid / 7, q = tid - bl*7;
            const float* pr = &lg[tid*8];
            float p0 = pr[0], p1 = pr[1], p2 = pr[2], p3 = pr[3], p4 = pr[4];
            float mx = fmaxf(fmaxf(fmaxf(p0, p1), fmaxf(p2, p3)), p4);
            float e0 = __expf(p0 - mx), e1 = __expf(p1 - mx), e2 = __expf(p2 - mx),
                  e3 = __expf(p3 - mx), e4 = __expf(p4 - mx);
            float inv = 1.0f / (e0 + e1 + e2 + e3 + e4);
            if (bl < valid) {
                float* op = out + (size_t)pvals[bl]*35 + q*5;
                op[0] = e0*inv; op[1] = e1*inv; op[2] = e2*inv; op[3] = e3*inv; op[4] = e4*inv;
            }
        }
    }
}

// ---------------- fallback path B: no workspace ----------------
template<typename T>
__device__ void direct_body(
    const T* __restrict__ x, const int* __restrict__ jid, int j64,
    const T* __restrict__ W1, const T* __restrict__ W1a,
    const T* __restrict__ W2, const T* __restrict__ W2a,
    const T* __restrict__ V,  const T* __restrict__ Va,
    float* __restrict__ out, float (*lds_z1)[NQ][128])
{
    const int tid = threadIdx.x;
    const int l = tid & 63, w = tid >> 6;
    #pragma unroll 1
    for (int t = 0; t < 4; ++t) {
        const int b = blockIdx.x * 16 + w * 4 + t;
        const int j = j64 ? jid[2*b] : jid[b];
        float xv = 0.0f;
        if (l < 35) xv = ldf(x + b*35 + l);
        #pragma unroll
        for (int q = 0; q < NQ; ++q) {
            const T* Wq  = W1  + q*768;
            const T* Waq = W1a + j*5376 + q*768;
            float a  = ldf(Wq + l)      + ldf(Waq + l);
            float bb = ldf(Wq + 64 + l) + ldf(Waq + 64 + l);
            #pragma unroll
            for (int i = 1; i <= 5; ++i) {
                float xi = __shfl(xv, q*5 + (i - 1), 64);
                a  = fmaf(xi, ldf(Wq + i*128 + l)      + ldf(Waq + i*128 + l),      a);
                bb = fmaf(xi, ldf(Wq + i*128 + 64 + l) + ldf(Waq + i*128 + 64 + l), bb);
            }
            lds_z1[w][q][l]      = sigmoidf_(a);
            lds_z1[w][q][64 + l] = sigmoidf_(bb);
        }
        __syncthreads();
        float accA[NQ], accB[NQ];
        {
            const float biasA = ldf(W2 + l)      + ldf(W2a + j*129*128 + l);
            const float biasB = ldf(W2 + 64 + l) + ldf(W2a + j*129*128 + 64 + l);
            #pragma unroll
            for (int q = 0; q < NQ; ++q) { accA[q] = biasA; accB[q] = biasB; }
        }
        #pragma unroll 1
        for (int k = 0; k < 128; ++k) {
            const int i = k + 1;
            const float wA = ldf(W2 + i*128 + l)      + ldf(W2a + (j*129 + i)*128 + l);
            const float wB = ldf(W2 + i*128 + 64 + l) + ldf(W2a + (j*129 + i)*128 + 64 + l);
            #pragma unroll
            for (int q = 0; q < NQ; ++q) {
                const float z = lds_z1[w][q][k];
                accA[q] = fmaf(wA, z, accA[q]);
                accB[q] = fmaf(wB, z, accB[q]);
            }
        }
        __syncthreads();
        #pragma unroll 1
        for (int q = 0; q < NQ; ++q) {
            const float zA = sigmoidf_(accA[q]);
            const float zB = sigmoidf_(accB[q]);
            const T* Vq  = V  + q*645;
            const T* Vaq = Va + j*4515 + q*645;
            float p[NO];
            #pragma unroll
            for (int o = 0; o < NO; ++o) {
                float vA = ldf(Vq + (1 + l)*5 + o)  + ldf(Vaq + (1 + l)*5 + o);
                float vB = ldf(Vq + (65 + l)*5 + o) + ldf(Vaq + (65 + l)*5 + o);
                p[o] = zA*vA + zB*vB;
            }
            #pragma unroll
            for (int off = 32; off > 0; off >>= 1) {
                #pragma unroll
                for (int o = 0; o < NO; ++o) p[o] += __shfl_xor(p[o], off, 64);
            }
            #pragma unroll
            for (int o = 0; o < NO; ++o) p[o] += ldf(Vq + o) + ldf(Vaq + o);
            float mx = fmaxf(fmaxf(fmaxf(p[0], p[1]), fmaxf(p[2], p[3])), p[4]);
            float e[NO], s = 0.0f;
            #pragma unroll
            for (int o = 0; o < NO; ++o) { e[o] = __expf(p[o] - mx); s += e[o]; }
            float inv = 1.0f / s;
            if (l < 5) out[b*35 + q*5 + l] = e[l] * inv;
        }
    }
}

__global__ __launch_bounds__(256) void calib_direct_kernel(
    const void* x, const int* jid,
    const void* W1, const void* W1a, const void* W2, const void* W2a,
    const void* V,  const void* Va, float* out)
{
    __shared__ __align__(16) float lds_z1[4][NQ][128];
    const int isb = probe_is_bf16((const unsigned int*)W1);
    const int j64 = probe_is_j64(jid);
    if (isb) direct_body(
        (const __hip_bfloat16*)x, jid, j64,
        (const __hip_bfloat16*)W1, (const __hip_bfloat16*)W1a,
        (const __hip_bfloat16*)W2, (const __hip_bfloat16*)W2a,
        (const __hip_bfloat16*)V,  (const __hip_bfloat16*)Va, out, lds_z1);
    else direct_body(
        (const float*)x, jid, j64,
        (const float*)W1, (const float*)W1a, (const float*)W2,
        (const float*)W2a, (const float*)V, (const float*)Va, out, lds_z1);
}

extern "C" void kernel_launch(void* const* d_in, const int* in_sizes, int n_in,
                              void* d_out, int out_size, void* d_ws, size_t ws_size,
                              hipStream_t stream)
{
    const void* x   = d_in[0];
    const int*  jid = (const int*)d_in[1];
    const void* W1  = d_in[2];
    const void* W1a = d_in[3];
    const void* W2  = d_in[4];
    const void* W2a = d_in[5];
    const void* V   = d_in[6];
    const void* Va  = d_in[7];
    float* out = (float*)d_out;

    if (ws_size >= WS_NEEDED_BYTES) {
        unsigned* ws32 = (unsigned*)d_ws;
        // 2 dispatches: combine + parallel no-init scatter, then main.
        fused_pre_kernel<<<NBLK_PRE, 256, 0, stream>>>(
            W1, W1a, W2, W2a, V, Va, jid, ws32);
        CalibrationNetwork_81329500717524_kernel<<<512, 256, 0, stream>>>(
            x, ws32, out);
    } else {
        calib_direct_kernel<<<B_TOT / 16, 256, 0, stream>>>(
            x, jid, W1, W1a, W2, W2a, V, Va, out);
    }
}

// Round 16
// 104.757 us; speedup vs baseline: 2.2766x; 1.0243x over previous
//
#include <hip/hip_runtime.h>
#include <hip/hip_bf16.h>

// Problem: B=16384, J=12, Q=7, O=5, H1=H2=128.  Output: fp32 [B,Q,O].
// R16 = R15 with the A1 staging bug fixed: wbuf[32] (was [16] -> OOB write +
// uninitialized LDS cols 32..63 read by MFMA -> NaN). Full 8x uint4 row store.
#define B_TOT 16384
#define NQ 7
#define NO 5

typedef float v4f __attribute__((ext_vector_type(4)));
typedef _Float16 v8h __attribute__((ext_vector_type(8)));

// ---------------- workspace layout (u32 slots) ----------------
#define WS_W1F  0
#define WS_W2F  (WS_W1F + 49152)
#define WS_V3F  (WS_W2F + 98304)
#define WS_W2L  (WS_V3F + 86016)
#define WS_V3L  (WS_W2L + 1536)
#define WS_PERM (WS_V3L + 1344)          // [12][16384], fragment at sblk*256
#define WS_HIST (WS_PERM + 12*16384)     // [64][12]
#define WS_ISB  (WS_HIST + 768)
#define WS_TOT_U32 (WS_ISB + 1)
#define WS_NEEDED_BYTES ((size_t)WS_TOT_U32 * 4)

#define CFRAG_TOT (49152 + 98304 + 86016 + 1536 + 1344)   // 236352
#define NBLK_COMBINE ((CFRAG_TOT + 255) / 256)            // 924
#define NBLK_SCATTER 64
#define NBLK_PRE (NBLK_COMBINE + NBLK_SCATTER)            // 988

// ---------------- helpers ----------------
__device__ __forceinline__ float ldf(const float* p) { return *p; }
__device__ __forceinline__ float ldf(const __hip_bfloat16* p) { return __bfloat162float(*p); }
__device__ __forceinline__ float sigmoidf_(float v) { return 1.0f / (1.0f + __expf(-v)); }
__device__ __forceinline__ unsigned short f2h(float f) {
    _Float16 h = (_Float16)f; return __builtin_bit_cast(unsigned short, h);
}
__device__ __forceinline__ float h2f(unsigned short u) {
    return (float)__builtin_bit_cast(_Float16, u);
}
__device__ __forceinline__ unsigned pack2(float a, float b) {
    return (unsigned)f2h(a) | ((unsigned)f2h(b) << 16);
}
__device__ __forceinline__ v8h bc8h(uint4 u) { return __builtin_bit_cast(v8h, u); }

// ---------------- probes (fallback path) ----------------
__device__ __forceinline__ int probe_is_bf16(const unsigned int* w1bits) {
    int hits = 0;
    for (int t = 0; t < 64; ++t) {
        unsigned lo = w1bits[t] & 0xFFFFu, e = (lo >> 7) & 0xFFu;
        if (lo == 0u || (e >= 100u && e <= 130u)) ++hits;
    }
    return hits >= 32;
}
__device__ __forceinline__ int probe_is_j64(const int* jid) {
    int o = 0;
    for (int t = 0; t < 64; ++t) o |= jid[2*t + 1];
    return (o == 0) ? 1 : 0;
}

// ---------------- combine body (R8/R9-verified) ----------------
template<typename T>
__device__ __forceinline__ void combine_body(
    int idx, const T* W1, const T* W1a, const T* W2, const T* W2a,
    const T* V, const T* Va, unsigned* ws32, float* wsF)
{
    if (idx < 49152) {                               // W1F
        int p = idx & 3, l = (idx >> 2) & 63, nt = (idx >> 8) & 7,
            ks = (idx >> 11) & 1, j = idx >> 12;
        int n = nt*16 + (l & 15);
        float v[2];
        #pragma unroll
        for (int s = 0; s < 2; ++s) {
            int k = ks*32 + ((l >> 4) << 3) + 2*p + s;
            v[s] = (k < 42) ? (ldf(W1 + k*128 + n) + ldf(W1a + j*5376 + k*128 + n)) : 0.0f;
        }
        ws32[WS_W1F + idx] = pack2(v[0], v[1]);
    } else if (idx < 49152 + 98304) {                // W2F
        int t = idx - 49152;
        int p = t & 3, l = (t >> 2) & 63, nt = (t >> 8) & 7,
            ks = (t >> 11) & 3, j = t >> 13;
        int n = nt*16 + (l & 15);
        float v[2];
        #pragma unroll
        for (int s = 0; s < 2; ++s) {
            int k = ks*32 + ((l >> 4) << 3) + 2*p + s;
            v[s] = ldf(W2 + k*128 + n) + ldf(W2a + (j*129 + k)*128 + n);
        }
        ws32[WS_W2F + t] = pack2(v[0], v[1]);
    } else if (idx < 49152 + 98304 + 86016) {        // V3F
        int t = idx - (49152 + 98304);
        int p = t & 3, l = (t >> 2) & 63, ks = (t >> 8) & 3;
        int jq = t >> 10, q = jq % 7, j = jq / 7;
        int n = l & 15;
        float v[2];
        #pragma unroll
        for (int s = 0; s < 2; ++s) {
            int k = ks*32 + ((l >> 4) << 3) + 2*p + s;
            v[s] = (n < 5) ? (ldf(V + q*645 + k*5 + n) + ldf(Va + j*4515 + q*645 + k*5 + n))
                           : 0.0f;
        }
        ws32[WS_V3F + t] = pack2(v[0], v[1]);
    } else if (idx < 49152 + 98304 + 86016 + 1536) { // W2L
        int t = idx - (49152 + 98304 + 86016);
        int j = t >> 7, n = t & 127;
        wsF[WS_W2L + t] = ldf(W2 + 128*128 + n) + ldf(W2a + (j*129 + 128)*128 + n);
    } else if (idx < CFRAG_TOT) {                    // V3L
        int t = idx - (49152 + 98304 + 86016 + 1536);
        int c = t & 15, jq = t >> 4, q = jq % 7, j = jq / 7;
        wsF[WS_V3L + t] = (c < 5)
            ? (ldf(V + q*645 + 640 + c) + ldf(Va + j*4515 + q*645 + 640 + c)) : 0.0f;
    }
}

// ---------------- fused pre: combine (0..923) + parallel scatter (924..987) --
__global__ __launch_bounds__(256) void fused_pre_kernel(
    const void* W1, const void* W1a, const void* W2, const void* W2a,
    const void* V,  const void* Va,  const int* jid, unsigned* ws32)
{
    __shared__ int sflag;
    __shared__ int wq[4][12];
    const int tid = threadIdx.x;
    int* wsI = (int*)ws32;

    if ((int)blockIdx.x < NBLK_COMBINE) {
        if (tid < 64) {
            unsigned wb = ((const unsigned*)W1)[tid];
            unsigned lo = wb & 0xFFFFu, e = (lo >> 7) & 0xFFu;
            unsigned long long mb = __ballot(lo == 0u || (e >= 100u && e <= 130u));
            if (tid == 0) sflag = (__popcll(mb) >= 32);
        }
        __syncthreads();
        const int isb = sflag;
        int idx = blockIdx.x * 256 + tid;
        if (idx >= CFRAG_TOT) return;
        float* wsF = (float*)ws32;
        if (isb) combine_body(idx,
            (const __hip_bfloat16*)W1, (const __hip_bfloat16*)W1a,
            (const __hip_bfloat16*)W2, (const __hip_bfloat16*)W2a,
            (const __hip_bfloat16*)V,  (const __hip_bfloat16*)Va, ws32, wsF);
        else combine_body(idx,
            (const float*)W1, (const float*)W1a, (const float*)W2,
            (const float*)W2a, (const float*)V, (const float*)Va, ws32, wsF);
    } else {
        const int sblk = blockIdx.x - NBLK_COMBINE;   // 0..63
        const int l = tid & 63, w = tid >> 6;
        if (sblk == 0 && tid < 64) {
            unsigned wb = ((const unsigned*)W1)[tid];
            unsigned lo = wb & 0xFFFFu, e = (lo >> 7) & 0xFFu;
            unsigned long long mb = __ballot(lo == 0u || (e >= 100u && e <= 130u));
            if (tid == 0) wsI[WS_ISB] = (__popcll(mb) >= 32);
        }
        if (tid < 64) {
            unsigned long long mo = __ballot(jid[2*tid + 1] != 0);
            if (tid == 0) sflag = (mo == 0ULL);
        }
        __syncthreads();
        const int j64 = sflag;
        const int idx = sblk * 256 + tid;
        const int j = j64 ? jid[2*idx] : jid[idx];

        int rloc = 0;
        int c[12];
        #pragma unroll
        for (int jj = 0; jj < 12; ++jj) {
            unsigned long long mk = __ballot(j == jj);
            c[jj] = (int)__popcll(mk);
            if (j == jj) rloc = (int)__popcll(mk & ((1ULL << l) - 1ULL));
        }
        if (l == 0) {
            #pragma unroll
            for (int jj = 0; jj < 12; ++jj) wq[w][jj] = c[jj];
        }
        __syncthreads();
        int pre = 0;
        #pragma unroll
        for (int w2 = 0; w2 < 4; ++w2)
            if (w2 < w) pre += wq[w2][j];
        wsI[WS_PERM + j*16384 + sblk*256 + pre + rloc] = idx;   // unique addr
        if (tid < 12)
            wsI[WS_HIST + sblk*12 + tid] =
                wq[0][tid] + wq[1][tid] + wq[2][tid] + wq[3][tid];
    }
}

// ---------------- main MFMA kernel: 8-b tiles, 4 blocks/CU, grid 1024 --------
#define Z_STRIDE 136   // u16 row stride (16B-aligned rows)
#define A_STRIDE 72
__global__ __launch_bounds__(256) void CalibrationNetwork_81329500717524_kernel(
    const void* xraw, const unsigned* __restrict__ ws32, float* __restrict__ out)
{
    __shared__ __align__(16) unsigned short z1L[64 * Z_STRIDE];  // 17408 B
    __shared__ __align__(16) unsigned short z2A[64 * Z_STRIDE];  // 17408 B
    __shared__ int pref[12 * 65];                                // 3120 B
    __shared__ int pvals[8];
    float* lg = (float*)z1L;          // logits alias: z1L dead after layer 2
    int* histL = (int*)z2A;           // startup alias

    const int* wsI = (const int*)ws32;
    const int tid = threadIdx.x;
    const int l = tid & 63, w = tid >> 6;
    const int quad = l >> 4, m = l & 15;
    const int isb = wsI[WS_ISB];

    // ---- startup: load 64x12 histogram, wave-parallel prefix (shfl_up) ----
    for (int i = tid; i < 768; i += 256) histL[i] = wsI[WS_HIST + i];
    __syncthreads();
    #pragma unroll
    for (int jo = 0; jo < 3; ++jo) {
        const int j = w*3 + jo;
        int vc = histL[l*12 + j];
        int s = vc;
        #pragma unroll
        for (int off = 1; off < 64; off <<= 1) {
            int t = __shfl_up(s, off, 64);
            if (l >= off) s += t;
        }
        pref[j*65 + l] = s - vc;            // exclusive prefix
        if (l == 63) pref[j*65 + 64] = s;   // judge total
    }
    __syncthreads();
    int cntR[12];
    #pragma unroll
    for (int jj = 0; jj < 12; ++jj) cntR[jj] = pref[jj*65 + 64];
    int totTiles = 0;
    #pragma unroll
    for (int jj = 0; jj < 12; ++jj) totTiles += (cntR[jj] + 7) >> 3;

    #pragma unroll 1
    for (int v = blockIdx.x; v < totTiles; v += gridDim.x) {
        int jT = 0, tT = 0, cj = 0, acc = 0;
        #pragma unroll
        for (int jj = 0; jj < 12; ++jj) {
            int c = cntR[jj], nt = (c + 7) >> 3;
            if (v >= acc && v < acc + nt) { jT = jj; tT = v - acc; cj = c; }
            acc += nt;
        }
        const int valid = min(8, cj - tT*8);

        __syncthreads();   // previous tile fully consumed

        // ---- staging 1: z1L bias col + perm lookup ----
        if (tid < 64) z1L[tid * Z_STRIDE] = 0x3C00;    // 1.0h (all 64 rows)
        if (tid < 8) {
            int bl = tid < valid ? tid : valid - 1;
            int r = tT*8 + bl;             // global rank within judge jT
            int k = 0;
            #pragma unroll                 // independent LDS loads -> one wait
            for (int kk = 1; kk < 64; ++kk)
                if (pref[jT*65 + kk] <= r) k = kk;
            pvals[tid] = wsI[WS_PERM + jT*16384 + k*256 + (r - pref[jT*65 + k])];
        }
        __syncthreads();
        // ---- staging 2: full-row A1 writes, cols 0..63 (data 0..41, pad 0) ----
        if (tid < 64) {
            unsigned wbuf[32];             // 64 u16 columns (fix: was [16])
            #pragma unroll
            for (int i = 0; i < 32; ++i) wbuf[i] = 0u;
            if (tid < 56) {
                int bl = tid / 7, q = tid - bl*7;
                int bg = pvals[bl];
                float x0, x1, x2, x3, x4;
                if (isb) {
                    const __hip_bfloat16* xp = (const __hip_bfloat16*)xraw + bg*35 + q*5;
                    x0 = ldf(xp); x1 = ldf(xp+1); x2 = ldf(xp+2); x3 = ldf(xp+3); x4 = ldf(xp+4);
                } else {
                    const float* xp = (const float*)xraw + bg*35 + q*5;
                    x0 = xp[0]; x1 = xp[1]; x2 = xp[2]; x3 = xp[3]; x4 = xp[4];
                }
                wbuf[q*3]     = 0x3C00u | ((unsigned)f2h(x0) << 16);
                wbuf[q*3 + 1] = pack2(x1, x2);
                wbuf[q*3 + 2] = pack2(x3, x4);
            }
            uint4* rowp = (uint4*)&z2A[tid * A_STRIDE];   // 144B rows, 16B aligned
            #pragma unroll
            for (int i = 0; i < 8; ++i) {
                uint4 u; u.x = wbuf[4*i]; u.y = wbuf[4*i+1];
                u.z = wbuf[4*i+2]; u.w = wbuf[4*i+3];
                rowp[i] = u;
            }
        }
        __syncthreads();

        // ---- layer 1: [64 x 64] x [64 x 128] ----
        {
            const uint4* BF = (const uint4*)(ws32 + WS_W1F) + jT*1024;
            #pragma unroll
            for (int nt2 = 0; nt2 < 2; ++nt2) {
                const int nt = w*2 + nt2;
                const uint4 b0 = BF[(0*8 + nt)*64 + l];
                const uint4 b1 = BF[(1*8 + nt)*64 + l];
                #pragma unroll 1
                for (int mt = 0; mt < 4; ++mt) {
                    const uint4 a0 = *(const uint4*)&z2A[(mt*16 + m)*A_STRIDE + quad*8];
                    const uint4 a1 = *(const uint4*)&z2A[(mt*16 + m)*A_STRIDE + 32 + quad*8];
                    v4f acc2 = {0.f, 0.f, 0.f, 0.f};
                    acc2 = __builtin_amdgcn_mfma_f32_16x16x32_f16(bc8h(a0), bc8h(b0), acc2, 0, 0, 0);
                    acc2 = __builtin_amdgcn_mfma_f32_16x16x32_f16(bc8h(a1), bc8h(b1), acc2, 0, 0, 0);
                    const int col = nt*16 + m;
                    #pragma unroll
                    for (int i = 0; i < 4; ++i) {
                        int row = mt*16 + quad*4 + i;
                        z1L[row*Z_STRIDE + 1 + col] = f2h(sigmoidf_(acc2[i]));
                    }
                }
            }
        }
        __syncthreads();

        // ---- layer 2: [64 x 128] x [128 x 128] + i'=128 fixup ----
        {
            if (tid < 64) z2A[tid * Z_STRIDE] = 0x3C00;   // z2 bias col
            const uint4* BF = (const uint4*)(ws32 + WS_W2F) + jT*2048;
            const float* w2l = (const float*)ws32 + WS_W2L + jT*128;
            #pragma unroll
            for (int nt2 = 0; nt2 < 2; ++nt2) {
                const int nt = w*2 + nt2;
                uint4 Bv[4];
                #pragma unroll
                for (int ks = 0; ks < 4; ++ks) Bv[ks] = BF[(ks*8 + nt)*64 + l];
                const float wl = w2l[nt*16 + m];
                #pragma unroll 1
                for (int mt = 0; mt < 4; ++mt) {
                    v4f acc2 = {0.f, 0.f, 0.f, 0.f};
                    #pragma unroll
                    for (int ks = 0; ks < 4; ++ks) {
                        const uint4 a = *(const uint4*)&z1L[(mt*16 + m)*Z_STRIDE + ks*32 + quad*8];
                        acc2 = __builtin_amdgcn_mfma_f32_16x16x32_f16(bc8h(a), bc8h(Bv[ks]), acc2, 0, 0, 0);
                    }
                    const int col = nt*16 + m;
                    #pragma unroll
                    for (int i = 0; i < 4; ++i) {
                        int row = mt*16 + quad*4 + i;
                        float zl = h2f(z1L[row*Z_STRIDE + 128]);   // z1[h=127]
                        float vv = acc2[i] + zl * wl;
                        z2A[row*Z_STRIDE + 1 + col] = f2h(sigmoidf_(vv));
                    }
                }
            }
        }
        __syncthreads();

        // ---- layer 3: per q [16 x 128] x [128 x 16(5)] + fixup -> logits ----
        // A M-rows: b-index; only b 0..7 exist -> clamp (m&7); discard bloc>=8.
        {
            const uint4* BF = (const uint4*)(ws32 + WS_V3F) + jT*7*256;
            const float* v3l = (const float*)ws32 + WS_V3L + jT*7*16;
            #pragma unroll 1
            for (int qi = 0; qi < 2; ++qi) {
                const int q = w + qi*4;
                if (q > 6) break;
                const int mrow = (m & 7)*7 + q;
                v4f acc2 = {0.f, 0.f, 0.f, 0.f};
                #pragma unroll
                for (int ks = 0; ks < 4; ++ks) {
                    const uint4 b = BF[q*256 + ks*64 + l];
                    const uint4 a = *(const uint4*)&z2A[mrow*Z_STRIDE + ks*32 + quad*8];
                    acc2 = __builtin_amdgcn_mfma_f32_16x16x32_f16(bc8h(a), bc8h(b), acc2, 0, 0, 0);
                }
                const float vl = v3l[q*16 + m];
                #pragma unroll
                for (int i = 0; i < 4; ++i) {
                    int bloc = quad*4 + i;
                    if (bloc < 8 && m < 5) {
                        float zl = h2f(z2A[(bloc*7 + q)*Z_STRIDE + 128]);  // z2[h'=127]
                        lg[(bloc*7 + q)*8 + m] = acc2[i] + zl * vl;
                    }
                }
            }
        }
        __syncthreads();

        // ---- softmax + store (56 rows) ----
        if (tid < 56) {
            int bl = tid / 7, q = tid - bl*7;
            const float* pr = &lg[tid*8];
            float p0 = pr[0], p1 = pr[1], p2 = pr[2], p3 = pr[3], p4 = pr[4];
            float mx = fmaxf(fmaxf(fmaxf(p0, p1), fmaxf(p2, p3)), p4);
            float e0 = __expf(p0 - mx), e1 = __expf(p1 - mx), e2 = __expf(p2 - mx),
                  e3 = __expf(p3 - mx), e4 = __expf(p4 - mx);
            float inv = 1.0f / (e0 + e1 + e2 + e3 + e4);
            if (bl < valid) {
                float* op = out + (size_t)pvals[bl]*35 + q*5;
                op[0] = e0*inv; op[1] = e1*inv; op[2] = e2*inv; op[3] = e3*inv; op[4] = e4*inv;
            }
        }
    }
}

// ---------------- fallback path B: no workspace ----------------
template<typename T>
__device__ void direct_body(
    const T* __restrict__ x, const int* __restrict__ jid, int j64,
    const T* __restrict__ W1, const T* __restrict__ W1a,
    const T* __restrict__ W2, const T* __restrict__ W2a,
    const T* __restrict__ V,  const T* __restrict__ Va,
    float* __restrict__ out, float (*lds_z1)[NQ][128])
{
    const int tid = threadIdx.x;
    const int l = tid & 63, w = tid >> 6;
    #pragma unroll 1
    for (int t = 0; t < 4; ++t) {
        const int b = blockIdx.x * 16 + w * 4 + t;
        const int j = j64 ? jid[2*b] : jid[b];
        float xv = 0.0f;
        if (l < 35) xv = ldf(x + b*35 + l);
        #pragma unroll
        for (int q = 0; q < NQ; ++q) {
            const T* Wq  = W1  + q*768;
            const T* Waq = W1a + j*5376 + q*768;
            float a  = ldf(Wq + l)      + ldf(Waq + l);
            float bb = ldf(Wq + 64 + l) + ldf(Waq + 64 + l);
            #pragma unroll
            for (int i = 1; i <= 5; ++i) {
                float xi = __shfl(xv, q*5 + (i - 1), 64);
                a  = fmaf(xi, ldf(Wq + i*128 + l)      + ldf(Waq + i*128 + l),      a);
                bb = fmaf(xi, ldf(Wq + i*128 + 64 + l) + ldf(Waq + i*128 + 64 + l), bb);
            }
            lds_z1[w][q][l]      = sigmoidf_(a);
            lds_z1[w][q][64 + l] = sigmoidf_(bb);
        }
        __syncthreads();
        float accA[NQ], accB[NQ];
        {
            const float biasA = ldf(W2 + l)      + ldf(W2a + j*129*128 + l);
            const float biasB = ldf(W2 + 64 + l) + ldf(W2a + j*129*128 + 64 + l);
            #pragma unroll
            for (int q = 0; q < NQ; ++q) { accA[q] = biasA; accB[q] = biasB; }
        }
        #pragma unroll 1
        for (int k = 0; k < 128; ++k) {
            const int i = k + 1;
            const float wA = ldf(W2 + i*128 + l)      + ldf(W2a + (j*129 + i)*128 + l);
            const float wB = ldf(W2 + i*128 + 64 + l) + ldf(W2a + (j*129 + i)*128 + 64 + l);
            #pragma unroll
            for (int q = 0; q < NQ; ++q) {
                const float z = lds_z1[w][q][k];
                accA[q] = fmaf(wA, z, accA[q]);
                accB[q] = fmaf(wB, z, accB[q]);
            }
        }
        __syncthreads();
        #pragma unroll 1
        for (int q = 0; q < NQ; ++q) {
            const float zA = sigmoidf_(accA[q]);
            const float zB = sigmoidf_(accB[q]);
            const T* Vq  = V  + q*645;
            const T* Vaq = Va + j*4515 + q*645;
            float p[NO];
            #pragma unroll
            for (int o = 0; o < NO; ++o) {
                float vA = ldf(Vq + (1 + l)*5 + o)  + ldf(Vaq + (1 + l)*5 + o);
                float vB = ldf(Vq + (65 + l)*5 + o) + ldf(Vaq + (65 + l)*5 + o);
                p[o] = zA*vA + zB*vB;
            }
            #pragma unroll
            for (int off = 32; off > 0; off >>= 1) {
                #pragma unroll
                for (int o = 0; o < NO; ++o) p[o] += __shfl_xor(p[o], off, 64);
            }
            #pragma unroll
            for (int o = 0; o < NO; ++o) p[o] += ldf(Vq + o) + ldf(Vaq + o);
            float mx = fmaxf(fmaxf(fmaxf(p[0], p[1]), fmaxf(p[2], p[3])), p[4]);
            float e[NO], s = 0.0f;
            #pragma unroll
            for (int o = 0; o < NO; ++o) { e[o] = __expf(p[o] - mx); s += e[o]; }
            float inv = 1.0f / s;
            if (l < 5) out[b*35 + q*5 + l] = e[l] * inv;
        }
    }
}

__global__ __launch_bounds__(256) void calib_direct_kernel(
    const void* x, const int* jid,
    const void* W1, const void* W1a, const void* W2, const void* W2a,
    const void* V,  const void* Va, float* out)
{
    __shared__ __align__(16) float lds_z1[4][NQ][128];
    const int isb = probe_is_bf16((const unsigned int*)W1);
    const int j64 = probe_is_j64(jid);
    if (isb) direct_body(
        (const __hip_bfloat16*)x, jid, j64,
        (const __hip_bfloat16*)W1, (const __hip_bfloat16*)W1a,
        (const __hip_bfloat16*)W2, (const __hip_bfloat16*)W2a,
        (const __hip_bfloat16*)V,  (const __hip_bfloat16*)Va, out, lds_z1);
    else direct_body(
        (const float*)x, jid, j64,
        (const float*)W1, (const float*)W1a, (const float*)W2,
        (const float*)W2a, (const float*)V, (const float*)Va, out, lds_z1);
}

extern "C" void kernel_launch(void* const* d_in, const int* in_sizes, int n_in,
                              void* d_out, int out_size, void* d_ws, size_t ws_size,
                              hipStream_t stream)
{
    const void* x   = d_in[0];
    const int*  jid = (const int*)d_in[1];
    const void* W1  = d_in[2];
    const void* W1a = d_in[3];
    const void* W2  = d_in[4];
    const void* W2a = d_in[5];
    const void* V   = d_in[6];
    const void* Va  = d_in[7];
    float* out = (float*)d_out;

    if (ws_size >= WS_NEEDED_BYTES) {
        unsigned* ws32 = (unsigned*)d_ws;
        // 2 dispatches: combine + parallel no-init scatter, then main.
        fused_pre_kernel<<<NBLK_PRE, 256, 0, stream>>>(
            W1, W1a, W2, W2a, V, Va, jid, ws32);
        CalibrationNetwork_81329500717524_kernel<<<1024, 256, 0, stream>>>(
            x, ws32, out);
    } else {
        calib_direct_kernel<<<B_TOT / 16, 256, 0, stream>>>(
            x, jid, W1, W1a, W2, W2a, V, Va, out);
    }
}